// Round 9
// baseline (27.856 us; speedup 1.0000x reference)
//
#include <hip/hip_runtime.h>
#include <math.h>

#define HI 128
#define WI 128
#define BB 2
#define PG 1024
#define NE (BB*PG)
#define NPROD 16            /* 2 batches x 8 segments of 128 gaussians */
#define NTILES 128          /* 2 batches x 64 tiles of 16x16 */
#define MAGIC     0xFEEDFACECAFEBEEFULL
#define MAGIC_HI  0xFEEDFACECAFE0000ULL
#define MASK_HI   0xFFFFFFFFFFFF0000ULL

#define OFF_ALPHA (BB*3*HI*WI)            /* 98304  */
#define OFF_ESTC  (OFF_ALPHA + BB*HI*WI)  /* 131072 */
#define OFF_ESTW  (OFF_ESTC + BB*PG*3)    /* 137216 */
#define OFF_RADII (OFF_ESTW + BB*PG)      /* 139264 */

struct PC {
  float px, py, ex, ey;
  float A, B, C, op;
  unsigned key;
  float radii;
};

__device__ __forceinline__ PC proj_cull(int e,
    const float* __restrict__ means, const float* __restrict__ opac,
    const float* __restrict__ scales, const float* __restrict__ rots,
    const float* __restrict__ vm, const float* __restrict__ pm)
{
  PC o;
  float mx = means[e*3+0], my = means[e*3+1], mz = means[e*3+2];

  float hom0 = pm[0]*mx + pm[1]*my + pm[2]*mz + pm[3];
  float hom1 = pm[4]*mx + pm[5]*my + pm[6]*mz + pm[7];
  float hom3 = pm[12]*mx + pm[13]*my + pm[14]*mz + pm[15];
  float p_w  = 1.0f / (hom3 + 1e-7f);
  float pp0 = hom0 * p_w, pp1 = hom1 * p_w;

  float pv0   = vm[0]*mx + vm[1]*my + vm[2]*mz  + vm[3];
  float pv1   = vm[4]*mx + vm[5]*my + vm[6]*mz  + vm[7];
  float depth = vm[8]*mx + vm[9]*my + vm[10]*mz + vm[11];

  float qr = rots[e*4+0], qx = rots[e*4+1], qy = rots[e*4+2], qz = rots[e*4+3];
  float qn = sqrtf(qr*qr + qx*qx + qy*qy + qz*qz);
  qr /= qn; qx /= qn; qy /= qn; qz /= qn;
  float R00 = 1.0f-2.0f*(qy*qy+qz*qz), R01 = 2.0f*(qx*qy-qr*qz), R02 = 2.0f*(qx*qz+qr*qy);
  float R10 = 2.0f*(qx*qy+qr*qz), R11 = 1.0f-2.0f*(qx*qx+qz*qz), R12 = 2.0f*(qy*qz-qr*qx);
  float R20 = 2.0f*(qx*qz-qr*qy), R21 = 2.0f*(qy*qz+qr*qx), R22 = 1.0f-2.0f*(qx*qx+qy*qy);

  float s0 = scales[e*3+0], s1 = scales[e*3+1], s2 = scales[e*3+2];
  float M00=R00*s0, M01=R01*s1, M02=R02*s2;
  float M10=R10*s0, M11=R11*s1, M12=R12*s2;
  float M20=R20*s0, M21=R21*s1, M22=R22*s2;
  float S00 = M00*M00+M01*M01+M02*M02;
  float S01 = M00*M10+M01*M11+M02*M12;
  float S02 = M00*M20+M01*M21+M02*M22;
  float S11 = M10*M10+M11*M11+M12*M12;
  float S12 = M10*M20+M11*M21+M12*M22;
  float S22 = M20*M20+M21*M21+M22*M22;

  const float fx = 128.0f, fyc = 128.0f;
  float tz = depth;
  float txc = fminf(fmaxf(pv0/tz, -0.65f), 0.65f) * tz;
  float tyc = fminf(fmaxf(pv1/tz, -0.65f), 0.65f) * tz;
  float J00 = fx/tz,  J02 = -fx*txc/(tz*tz);
  float J11 = fyc/tz, J12 = -fyc*tyc/(tz*tz);

  float T00 = J00*vm[0] + J02*vm[8];
  float T01 = J00*vm[1] + J02*vm[9];
  float T02 = J00*vm[2] + J02*vm[10];
  float T10 = J11*vm[4] + J12*vm[8];
  float T11 = J11*vm[5] + J12*vm[9];
  float T12 = J11*vm[6] + J12*vm[10];

  float TS00 = T00*S00 + T01*S01 + T02*S02;
  float TS01 = T00*S01 + T01*S11 + T02*S12;
  float TS02 = T00*S02 + T01*S12 + T02*S22;
  float TS10 = T10*S00 + T11*S01 + T12*S02;
  float TS11 = T10*S01 + T11*S11 + T12*S12;
  float TS12 = T10*S02 + T11*S12 + T12*S22;

  float c00 = TS00*T00 + TS01*T01 + TS02*T02 + 0.3f;
  float c01 = TS00*T10 + TS01*T11 + TS02*T12;
  float c11 = TS10*T10 + TS11*T11 + TS12*T12 + 0.3f;

  float det = c00*c11 - c01*c01;
  bool valid = (depth > 0.2f) && (det > 1e-12f);
  float inv_det = 1.0f / (det > 1e-12f ? det : 1.0f);
  o.A =  c11 * inv_det;
  o.B = -c01 * inv_det;
  o.C =  c00 * inv_det;
  float mid = 0.5f * (c00 + c11);
  float lam = mid + sqrtf(fmaxf(mid*mid - det, 0.1f));
  o.radii = valid ? ceilf(3.0f * sqrtf(lam)) : 0.0f;

  o.px = ((pp0 + 1.0f)*WI - 1.0f)*0.5f;
  o.py = ((pp1 + 1.0f)*HI - 1.0f)*0.5f;

  float opv = opac[e];
  o.op = opv;
  float tau = logf(255.0f * opv);
  bool rok = valid && (tau > 0.0f);
  o.ex = rok ? sqrtf(2.0f*tau*c00) + 0.02f : -1e9f;
  o.ey = rok ? sqrtf(2.0f*tau*c11) + 0.02f : -1e9f;

  unsigned u = __float_as_uint(depth);
  o.key = (u >> 31) ? ~u : (u | 0x80000000u);
  return o;
}

__device__ __forceinline__ void sh_color(int e,
    const float* __restrict__ sh, const float* __restrict__ means,
    const float* __restrict__ campos, float col[3])
{
  float mx = means[e*3+0], my = means[e*3+1], mz = means[e*3+2];
  float dxr = mx - campos[0], dyr = my - campos[1], dzr = mz - campos[2];
  float dn = sqrtf(dxr*dxr + dyr*dyr + dzr*dzr);
  float x = dxr/dn, y = dyr/dn, z = dzr/dn;
  float xx=x*x, yy=y*y, zz=z*z, xy=x*y, yz=y*z, xz=x*z;
  const float* S = sh + e*48;
  #pragma unroll
  for (int c = 0; c < 3; ++c) {
    float r = 0.28209479177387814f * S[0+c];
    r -= 0.4886025119029199f * y * S[3+c];
    r += 0.4886025119029199f * z * S[6+c];
    r -= 0.4886025119029199f * x * S[9+c];
    r += 1.0925484305920792f  * xy * S[12+c];
    r += -1.0925484305920792f * yz * S[15+c];
    r += 0.31539156525252005f * (2.0f*zz-xx-yy) * S[18+c];
    r += -1.0925484305920792f * xz * S[21+c];
    r += 0.5462742152960396f  * (xx-yy) * S[24+c];
    r += -0.5900435899266435f * y * (3.0f*xx-yy) * S[27+c];
    r += 2.890611442640554f   * xy * z * S[30+c];
    r += -0.4570457994644658f * y * (4.0f*zz-xx-yy) * S[33+c];
    r += 0.3731763325901154f  * z * (2.0f*zz-3.0f*xx-3.0f*yy) * S[36+c];
    r += -0.4570457994644658f * x * (4.0f*zz-xx-yy) * S[39+c];
    r += 1.445305721320277f   * z * (xx-yy) * S[42+c];
    r += -0.5900435899266435f * x * (xx-3.0f*yy) * S[45+c];
    col[c] = fmaxf(r + 0.5f, 0.0f);
  }
}

__global__ __launch_bounds__(256) void fused_kernel(
    const float* __restrict__ means, const float* __restrict__ sh,
    const float* __restrict__ opac, const float* __restrict__ scales,
    const float* __restrict__ rots, const float* __restrict__ vm,
    const float* __restrict__ pm, const float* __restrict__ campos,
    const float* __restrict__ target, const float* __restrict__ bg,
    float4* __restrict__ culk, unsigned int* __restrict__ keyar,
    float4* __restrict__ recAg, float4* __restrict__ recBg,
    float4* __restrict__ colCg,
    float4* __restrict__ pval, int* __restrict__ pgid,
    unsigned long long* __restrict__ prodflags,
    unsigned long long* __restrict__ tileflags,
    float* __restrict__ out)
{
  const int t = threadIdx.x;
  const int blk = blockIdx.x;

  __shared__ unsigned long long skey[PG];
  __shared__ float4 recA[256], recB[256], colC[256], stgt[256];
  __shared__ float  wmat[32][264];
  __shared__ int    scount;
  __shared__ int    scnt[64], soff[65];

  if (blk < NPROD) {
    // ============== producer (then reducer) block ==============
    const int batch = blk >> 3, seg = blk & 7;
    const int e_own = (batch << 10) + seg*128 + (t & 127);

    if (t < 128) {
      PC g = proj_cull(e_own, means, opac, scales, rots, vm, pm);
      float col[3]; sh_color(e_own, sh, means, campos, col);
      culk[e_own]  = make_float4(g.px, g.py, g.ex, g.ey);
      keyar[e_own] = g.key;
      recAg[e_own] = make_float4(g.px, g.py, g.A, g.B);
      recBg[e_own] = make_float4(g.C, g.op, 0.f, 0.f);
      colCg[e_own] = make_float4(col[0], col[1], col[2], 0.f);
      out[OFF_RADII + e_own] = g.radii;
    }
    __syncthreads();
    if (t == 0) {
      __threadfence();
      atomicExch(&prodflags[blk], MAGIC);
    }

    // -------- reducer role --------
    float* acc = &wmat[0][0];                // 128*4 floats
    for (int i = t; i < 128*4; i += 256) acc[i] = 0.f;

    if (t < 64) {
      unsigned long long v;
      do { v = atomicAdd(&tileflags[batch*64 + t], 0ull);
           if ((v & MASK_HI) != MAGIC_HI) __builtin_amdgcn_s_sleep(1);
      } while ((v & MASK_HI) != MAGIC_HI);
      scnt[t] = (int)(v & 0xFFFFull);
    }
    __syncthreads();
    __threadfence();

    if (t == 0) {
      int s = 0;
      for (int i = 0; i < 64; ++i) { soff[i] = s; s += scnt[i]; }
      soff[64] = s;
    }
    __syncthreads();
    int E = soff[64];

    for (int idx = t; idx < E; idx += 256) {
      int lo = 0, hi = 63;
      while (lo < hi) { int mid = (lo+hi+1) >> 1; if (soff[mid] <= idx) lo = mid; else hi = mid-1; }
      int tb = batch*64 + lo;
      int j = idx - soff[lo];
      int gi = pgid[tb*PG + j];
      if ((gi >> 7) == seg) {
        float4 v = pval[tb*PG + j];
        int s = gi & 127;
        atomicAdd(&acc[s*4+0], v.x);
        atomicAdd(&acc[s*4+1], v.y);
        atomicAdd(&acc[s*4+2], v.z);
        atomicAdd(&acc[s*4+3], v.w);
      }
    }
    __syncthreads();

    if (t < 128) {
      out[OFF_ESTC + e_own*3 + 0] = acc[(t&127)*4+0];
      out[OFF_ESTC + e_own*3 + 1] = acc[(t&127)*4+1];
      out[OFF_ESTC + e_own*3 + 2] = acc[(t&127)*4+2];
      out[OFF_ESTW + e_own]       = acc[(t&127)*4+3];
    }
    return;
  }

  // ==================== tile block ====================
  const int tblk = blk - NPROD;
  const int b = tblk >> 6, tile = tblk & 63;
  const int tx0i = (tile & 7) * 16, ty0i = (tile >> 3) * 16;
  const int xi = tx0i + (t & 15), yi = ty0i + (t >> 4);
  const float fxp = (float)xi, fyp = (float)yi;
  const float rx0 = (float)tx0i, ry0 = (float)ty0i;

  if (t == 0) scount = 0;
  stgt[t] = make_float4(target[((b*3+0)*HI + yi)*WI + xi],
                        target[((b*3+1)*HI + yi)*WI + xi],
                        target[((b*3+2)*HI + yi)*WI + xi], 1.0f);

  if (t < 8) {
    while (atomicAdd(&prodflags[b*8 + t], 0ull) != MAGIC) __builtin_amdgcn_s_sleep(1);
  }
  __syncthreads();
  __threadfence();

  for (int k = 0; k < 4; ++k) {
    int ci = k*256 + t;
    float4 cv = culk[(b<<10) + ci];
    bool ok = (cv.x + cv.z >= rx0) && (cv.x - cv.z <= rx0 + 15.0f)
           && (cv.y + cv.w >= ry0) && (cv.y - cv.w <= ry0 + 15.0f);
    if (ok) {
      int pos = atomicAdd(&scount, 1);
      skey[pos] = (((unsigned long long)keyar[(b<<10) + ci]) << 10) | (unsigned)ci;
    }
  }
  __syncthreads();
  int total = scount;

  if (total > 1) {
    if (total <= 64) {
      if (t < 64) {
        unsigned long long v = (t < total) ? skey[t] : ~0ull;
        #pragma unroll
        for (int k = 2; k <= 64; k <<= 1) {
          bool dirAsc = ((t & k) == 0);
          #pragma unroll
          for (int j = k >> 1; j > 0; j >>= 1) {
            unsigned long long o = __shfl_xor(v, j, 64);
            bool takeMin = (((t & j) == 0) == dirAsc);
            bool less = v < o;
            v = (takeMin == less) ? v : o;
          }
        }
        if (t < total) skey[t] = v;
      }
      __syncthreads();
    } else {
      int M = 64; while (M < total) M <<= 1;
      for (int i = total + t; i < M; i += 256) skey[i] = ~0ull;
      __syncthreads();
      for (int k = 2; k <= M; k <<= 1)
        for (int j = k >> 1; j > 0; j >>= 1) {
          for (int base = t; base < M; base += 256) {
            int ixj = base ^ j;
            if (ixj > base) {
              unsigned long long a = skey[base], q = skey[ixj];
              bool up = ((base & k) == 0);
              if ((a > q) == up) { skey[base] = q; skey[ixj] = a; }
            }
          }
          __syncthreads();
        }
    }
  }

  float T = 1.0f, a0 = 0.f, a1 = 0.f, a2 = 0.f;

  for (int p0 = 0; p0 < total; p0 += 256) {
    int lim = min(256, total - p0);
    if (p0 + t < total) {
      int gi = (int)(skey[p0 + t] & 1023u);
      int e = (b<<10) + gi;
      float4 rb = recBg[e];
      rb.z = __int_as_float(gi);
      recA[t] = recAg[e]; recB[t] = rb; colC[t] = colCg[e];
    }
    __syncthreads();

    for (int c0 = 0; c0 < lim; c0 += 32) {
      int cc = min(32, lim - c0);
      for (int i = 0; i < cc; ++i) {
        float4 qa = recA[c0+i], qb = recB[c0+i], qc = colC[c0+i];
        float dx = qa.x - fxp, dy = qa.y - fyp;
        float power = -0.5f*(qa.z*dx*dx + qb.x*dy*dy) - qa.w*dx*dy;
        float alpha = fminf(0.99f, qb.y * __expf(power));
        bool keep = (power <= 0.0f) && (alpha >= (1.0f/255.0f));
        float w_ = keep ? alpha * T : 0.0f;
        a0 += w_*qc.x; a1 += w_*qc.y; a2 += w_*qc.z;
        T -= w_;
        wmat[i][t] = w_;
      }
      __syncthreads();
      int row = t >> 3, j = t & 7;
      if (row < cc) {
        float e0=0.f, e1=0.f, e2=0.f, ew=0.f;
        #pragma unroll 8
        for (int k = 0; k < 32; ++k) {
          int p = j + 8*k;
          float w_ = wmat[row][p];
          float4 tg = stgt[p];
          e0 += w_*tg.x; e1 += w_*tg.y; e2 += w_*tg.z; ew += w_;
        }
        #pragma unroll
        for (int o = 4; o; o >>= 1) {
          e0 += __shfl_down(e0, o, 8); e1 += __shfl_down(e1, o, 8);
          e2 += __shfl_down(e2, o, 8); ew += __shfl_down(ew, o, 8);
        }
        if (j == 0) {
          int idx = p0 + c0 + row;
          pgid[tblk*PG + idx] = __float_as_int(recB[c0+row].z);
          pval[tblk*PG + idx] = make_float4(e0, e1, e2, ew);
        }
      }
      __syncthreads();
    }
  }

  out[((b*3+0)*HI + yi)*WI + xi] = a0 + T * bg[b*3+0];
  out[((b*3+1)*HI + yi)*WI + xi] = a1 + T * bg[b*3+1];
  out[((b*3+2)*HI + yi)*WI + xi] = a2 + T * bg[b*3+2];
  out[OFF_ALPHA + (b*HI + yi)*WI + xi] = 1.0f - T;

  __syncthreads();
  if (t == 0) {
    __threadfence();
    atomicExch(&tileflags[tblk], MAGIC_HI | (unsigned long long)total);
  }
}

extern "C" void kernel_launch(void* const* d_in, const int* in_sizes, int n_in,
                              void* d_out, int out_size, void* d_ws, size_t ws_size,
                              hipStream_t stream) {
  const float* means  = (const float*)d_in[0];
  const float* sh     = (const float*)d_in[1];
  const float* opac   = (const float*)d_in[2];
  const float* scales = (const float*)d_in[3];
  const float* rots   = (const float*)d_in[4];
  const float* target = (const float*)d_in[5];
  const float* bg     = (const float*)d_in[6];
  const float* vm     = (const float*)d_in[7];
  const float* pm     = (const float*)d_in[8];
  const float* campos = (const float*)d_in[9];
  float* out = (float*)d_out;

  float4* culk  = (float4*)d_ws;             // NE float4
  float4* recAg = culk + NE;
  float4* recBg = recAg + NE;
  float4* colCg = recBg + NE;
  float4* pval  = colCg + NE;                // 128*1024 float4 = 2MB
  unsigned int* keyar = (unsigned int*)(pval + NTILES*PG);   // NE u32
  int* pgid = (int*)(keyar + NE);            // 512KB
  unsigned long long* prodflags = (unsigned long long*)(pgid + NTILES*PG);
  unsigned long long* tileflags = prodflags + NPROD;

  fused_kernel<<<NPROD + NTILES, 256, 0, stream>>>(
      means, sh, opac, scales, rots, vm, pm, campos, target, bg,
      culk, keyar, recAg, recBg, colCg, pval, pgid,
      prodflags, tileflags, out);
}

// Round 10
// 26.990 us; speedup vs baseline: 1.0321x; 1.0321x over previous
//
#include <hip/hip_runtime.h>
#include <math.h>

#define HI 128
#define WI 128
#define BB 2
#define PG 1024
#define NE (BB*PG)
#define TPB 128            /* tiles per batch: 16 cols x 8 rows of 8x16 px */
#define NT2 (BB*TPB)       /* 256 tile blocks */
#define NRED 16            /* 2 batches x 8 segments of 128 gaussians */
#define MAGIC_HI  0xFEEDFACECAFE0000ULL
#define MASK_HI   0xFFFFFFFFFFFF0000ULL

#define OFF_ALPHA (BB*3*HI*WI)            /* 98304  */
#define OFF_ESTC  (OFF_ALPHA + BB*HI*WI)  /* 131072 */
#define OFF_ESTW  (OFF_ESTC + BB*PG*3)    /* 137216 */
#define OFF_RADII (OFF_ESTW + BB*PG)      /* 139264 */

struct PC {
  float px, py, ex, ey;
  float A, B, C, op;
  unsigned key;
  float radii;
};

__device__ __forceinline__ PC proj_cull(int e,
    const float* __restrict__ means, const float* __restrict__ opac,
    const float* __restrict__ scales, const float* __restrict__ rots,
    const float* __restrict__ vm, const float* __restrict__ pm)
{
  PC o;
  float mx = means[e*3+0], my = means[e*3+1], mz = means[e*3+2];

  float hom0 = pm[0]*mx + pm[1]*my + pm[2]*mz + pm[3];
  float hom1 = pm[4]*mx + pm[5]*my + pm[6]*mz + pm[7];
  float hom3 = pm[12]*mx + pm[13]*my + pm[14]*mz + pm[15];
  float p_w  = 1.0f / (hom3 + 1e-7f);
  float pp0 = hom0 * p_w, pp1 = hom1 * p_w;

  float pv0   = vm[0]*mx + vm[1]*my + vm[2]*mz  + vm[3];
  float pv1   = vm[4]*mx + vm[5]*my + vm[6]*mz  + vm[7];
  float depth = vm[8]*mx + vm[9]*my + vm[10]*mz + vm[11];

  float qr = rots[e*4+0], qx = rots[e*4+1], qy = rots[e*4+2], qz = rots[e*4+3];
  float qn = sqrtf(qr*qr + qx*qx + qy*qy + qz*qz);
  qr /= qn; qx /= qn; qy /= qn; qz /= qn;
  float R00 = 1.0f-2.0f*(qy*qy+qz*qz), R01 = 2.0f*(qx*qy-qr*qz), R02 = 2.0f*(qx*qz+qr*qy);
  float R10 = 2.0f*(qx*qy+qr*qz), R11 = 1.0f-2.0f*(qx*qx+qz*qz), R12 = 2.0f*(qy*qz-qr*qx);
  float R20 = 2.0f*(qx*qz-qr*qy), R21 = 2.0f*(qy*qz+qr*qx), R22 = 1.0f-2.0f*(qx*qx+qy*qy);

  float s0 = scales[e*3+0], s1 = scales[e*3+1], s2 = scales[e*3+2];
  float M00=R00*s0, M01=R01*s1, M02=R02*s2;
  float M10=R10*s0, M11=R11*s1, M12=R12*s2;
  float M20=R20*s0, M21=R21*s1, M22=R22*s2;
  float S00 = M00*M00+M01*M01+M02*M02;
  float S01 = M00*M10+M01*M11+M02*M12;
  float S02 = M00*M20+M01*M21+M02*M22;
  float S11 = M10*M10+M11*M11+M12*M12;
  float S12 = M10*M20+M11*M21+M12*M22;
  float S22 = M20*M20+M21*M21+M22*M22;

  const float fx = 128.0f, fyc = 128.0f;
  float tz = depth;
  float txc = fminf(fmaxf(pv0/tz, -0.65f), 0.65f) * tz;
  float tyc = fminf(fmaxf(pv1/tz, -0.65f), 0.65f) * tz;
  float J00 = fx/tz,  J02 = -fx*txc/(tz*tz);
  float J11 = fyc/tz, J12 = -fyc*tyc/(tz*tz);

  float T00 = J00*vm[0] + J02*vm[8];
  float T01 = J00*vm[1] + J02*vm[9];
  float T02 = J00*vm[2] + J02*vm[10];
  float T10 = J11*vm[4] + J12*vm[8];
  float T11 = J11*vm[5] + J12*vm[9];
  float T12 = J11*vm[6] + J12*vm[10];

  float TS00 = T00*S00 + T01*S01 + T02*S02;
  float TS01 = T00*S01 + T01*S11 + T02*S12;
  float TS02 = T00*S02 + T01*S12 + T02*S22;
  float TS10 = T10*S00 + T11*S01 + T12*S02;
  float TS11 = T10*S01 + T11*S11 + T12*S12;
  float TS12 = T10*S02 + T11*S12 + T12*S22;

  float c00 = TS00*T00 + TS01*T01 + TS02*T02 + 0.3f;
  float c01 = TS00*T10 + TS01*T11 + TS02*T12;
  float c11 = TS10*T10 + TS11*T11 + TS12*T12 + 0.3f;

  float det = c00*c11 - c01*c01;
  bool valid = (depth > 0.2f) && (det > 1e-12f);
  float inv_det = 1.0f / (det > 1e-12f ? det : 1.0f);
  o.A =  c11 * inv_det;
  o.B = -c01 * inv_det;
  o.C =  c00 * inv_det;
  float mid = 0.5f * (c00 + c11);
  float lam = mid + sqrtf(fmaxf(mid*mid - det, 0.1f));
  o.radii = valid ? ceilf(3.0f * sqrtf(lam)) : 0.0f;

  o.px = ((pp0 + 1.0f)*WI - 1.0f)*0.5f;
  o.py = ((pp1 + 1.0f)*HI - 1.0f)*0.5f;

  float opv = opac[e];
  o.op = opv;
  float tau = logf(255.0f * opv);
  bool rok = valid && (tau > 0.0f);
  o.ex = rok ? sqrtf(2.0f*tau*c00) + 0.02f : -1e9f;
  o.ey = rok ? sqrtf(2.0f*tau*c11) + 0.02f : -1e9f;

  unsigned u = __float_as_uint(depth);
  o.key = (u >> 31) ? ~u : (u | 0x80000000u);
  return o;
}

__device__ __forceinline__ void sh_color(int e,
    const float* __restrict__ sh, const float* __restrict__ means,
    const float* __restrict__ campos, float col[3])
{
  float mx = means[e*3+0], my = means[e*3+1], mz = means[e*3+2];
  float dxr = mx - campos[0], dyr = my - campos[1], dzr = mz - campos[2];
  float dn = sqrtf(dxr*dxr + dyr*dyr + dzr*dzr);
  float x = dxr/dn, y = dyr/dn, z = dzr/dn;
  float xx=x*x, yy=y*y, zz=z*z, xy=x*y, yz=y*z, xz=x*z;
  const float* S = sh + e*48;
  #pragma unroll
  for (int c = 0; c < 3; ++c) {
    float r = 0.28209479177387814f * S[0+c];
    r -= 0.4886025119029199f * y * S[3+c];
    r += 0.4886025119029199f * z * S[6+c];
    r -= 0.4886025119029199f * x * S[9+c];
    r += 1.0925484305920792f  * xy * S[12+c];
    r += -1.0925484305920792f * yz * S[15+c];
    r += 0.31539156525252005f * (2.0f*zz-xx-yy) * S[18+c];
    r += -1.0925484305920792f * xz * S[21+c];
    r += 0.5462742152960396f  * (xx-yy) * S[24+c];
    r += -0.5900435899266435f * y * (3.0f*xx-yy) * S[27+c];
    r += 2.890611442640554f   * xy * z * S[30+c];
    r += -0.4570457994644658f * y * (4.0f*zz-xx-yy) * S[33+c];
    r += 0.3731763325901154f  * z * (2.0f*zz-3.0f*xx-3.0f*yy) * S[36+c];
    r += -0.4570457994644658f * x * (4.0f*zz-xx-yy) * S[39+c];
    r += 1.445305721320277f   * z * (xx-yy) * S[42+c];
    r += -0.5900435899266435f * x * (xx-3.0f*yy) * S[45+c];
    col[c] = fmaxf(r + 0.5f, 0.0f);
  }
}

__global__ __launch_bounds__(256) void fused_kernel(
    const float* __restrict__ means, const float* __restrict__ sh,
    const float* __restrict__ opac, const float* __restrict__ scales,
    const float* __restrict__ rots, const float* __restrict__ vm,
    const float* __restrict__ pm, const float* __restrict__ campos,
    const float* __restrict__ target, const float* __restrict__ bg,
    float4* __restrict__ pval, int* __restrict__ pgid,
    unsigned long long* __restrict__ tileflags,
    float* __restrict__ out)
{
  const int t = threadIdx.x;
  const int blk = blockIdx.x;

  __shared__ unsigned long long skey[PG];
  __shared__ float4 recA[256], recB[256], colC[256];
  __shared__ float4 stgt[128];
  __shared__ float  wmat[2][32][132];       /* stride 132 -> 2-way banks */
  __shared__ int    scount;
  __shared__ int    scnt[128], soff[129];

  if (blk < NT2) {
    // ==================== tile block: 8x16 pixels ====================
    const int b = blk >> 7, tile = blk & 127;
    const int tx0i = (tile & 15) * 8, ty0i = (tile >> 4) * 16;
    const int xi = tx0i + (t & 7), yi = ty0i + (t >> 3);   // valid for t<128
    const float rx0 = (float)tx0i, ry0 = (float)ty0i;
    const float fxp = (float)xi, fyp = (float)yi;

    if (t == 0) scount = 0;
    if (t < 128) {
      stgt[t] = make_float4(target[((b*3+0)*HI + yi)*WI + xi],
                            target[((b*3+1)*HI + yi)*WI + xi],
                            target[((b*3+2)*HI + yi)*WI + xi], 1.0f);
    }
    __syncthreads();

    // scan all 1024 gaussians (4 per thread), compact survivors
    for (int k = 0; k < 4; ++k) {
      int ci = k*256 + t;
      PC r = proj_cull((b<<10)+ci, means, opac, scales, rots, vm, pm);
      bool ok = (r.px + r.ex >= rx0) && (r.px - r.ex <= rx0 + 7.0f)
             && (r.py + r.ey >= ry0) && (r.py - r.ey <= ry0 + 15.0f);
      if (ok) {
        int pos = atomicAdd(&scount, 1);
        skey[pos] = (((unsigned long long)r.key) << 10) | (unsigned)ci;
      }
    }
    __syncthreads();
    int total = scount;

    // sort survivors by (depth,idx)
    if (total > 1) {
      if (total <= 64) {
        if (t < 64) {
          unsigned long long v = (t < total) ? skey[t] : ~0ull;
          #pragma unroll
          for (int k = 2; k <= 64; k <<= 1) {
            bool dirAsc = ((t & k) == 0);
            #pragma unroll
            for (int j = k >> 1; j > 0; j >>= 1) {
              unsigned long long o = __shfl_xor(v, j, 64);
              bool takeMin = (((t & j) == 0) == dirAsc);
              bool less = v < o;
              v = (takeMin == less) ? v : o;
            }
          }
          if (t < total) skey[t] = v;
        }
        __syncthreads();
      } else {
        int M = 64; while (M < total) M <<= 1;
        for (int i = total + t; i < M; i += 256) skey[i] = ~0ull;
        __syncthreads();
        for (int k = 2; k <= M; k <<= 1)
          for (int j = k >> 1; j > 0; j >>= 1) {
            for (int base = t; base < M; base += 256) {
              int ixj = base ^ j;
              if (ixj > base) {
                unsigned long long a = skey[base], q = skey[ixj];
                bool up = ((base & k) == 0);
                if ((a > q) == up) { skey[base] = q; skey[ixj] = a; }
              }
            }
            __syncthreads();
          }
      }
    }

    float T = 1.0f, a0 = 0.f, a1 = 0.f, a2 = 0.f;

    for (int p0 = 0; p0 < total; p0 += 256) {
      int lim = min(256, total - p0);
      // stage up to 256 survivors: full record + SH color (1 per thread)
      if (p0 + t < total) {
        int gi = (int)(skey[p0 + t] & 1023u);
        int e = (b<<10) + gi;
        PC r = proj_cull(e, means, opac, scales, rots, vm, pm);
        float col[3]; sh_color(e, sh, means, campos, col);
        recA[t] = make_float4(r.px, r.py, r.A, r.B);
        recB[t] = make_float4(r.C, r.op, __int_as_float(gi), 0.f);
        colC[t] = make_float4(col[0], col[1], col[2], 0.f);
      }
      __syncthreads();

      int nch = (lim + 31) >> 5;
      for (int ch = 0; ch < nch; ++ch) {
        int c0 = ch << 5;
        int cc = min(32, lim - c0);
        int buf = ch & 1;
        if (t < 128) {
          // serial blend of this chunk (pixel-per-thread)
          for (int i = 0; i < cc; ++i) {
            float4 qa = recA[c0+i], qb = recB[c0+i], qc = colC[c0+i];
            float dx = qa.x - fxp, dy = qa.y - fyp;
            float power = -0.5f*(qa.z*dx*dx + qb.x*dy*dy) - qa.w*dx*dy;
            float alpha = fminf(0.99f, qb.y * __expf(power));
            bool keep = (power <= 0.0f) && (alpha >= (1.0f/255.0f));
            float w_ = keep ? alpha * T : 0.0f;
            a0 += w_*qc.x; a1 += w_*qc.y; a2 += w_*qc.z;
            T -= w_;
            wmat[buf][i][t] = w_;
          }
        } else if (ch > 0) {
          // reduce previous chunk (always full 32) concurrently
          int ts = t - 128;
          int row = ts >> 2, j = ts & 3;
          int pc0 = (ch-1) << 5;
          float e0=0.f, e1=0.f, e2=0.f, ew=0.f;
          #pragma unroll 8
          for (int k = 0; k < 32; ++k) {
            int p = j + 4*k;
            float w_ = wmat[buf^1][row][p];
            float4 tg = stgt[p];
            e0 += w_*tg.x; e1 += w_*tg.y; e2 += w_*tg.z; ew += w_;
          }
          e0 += __shfl_down(e0, 2, 4); e1 += __shfl_down(e1, 2, 4);
          e2 += __shfl_down(e2, 2, 4); ew += __shfl_down(ew, 2, 4);
          e0 += __shfl_down(e0, 1, 4); e1 += __shfl_down(e1, 1, 4);
          e2 += __shfl_down(e2, 1, 4); ew += __shfl_down(ew, 1, 4);
          if (j == 0) {
            int idx = p0 + pc0 + row;
            pgid[blk*PG + idx] = __float_as_int(recB[pc0+row].z);
            pval[blk*PG + idx] = make_float4(e0, e1, e2, ew);
          }
        }
        __syncthreads();
      }
      // reduce the final chunk of this stage
      {
        int lc0 = (nch-1) << 5;
        int lcc = lim - lc0;
        int lbuf = (nch-1) & 1;
        if (t < 128) {
          int row = t >> 2, j = t & 3;
          if (row < lcc) {
            float e0=0.f, e1=0.f, e2=0.f, ew=0.f;
            #pragma unroll 8
            for (int k = 0; k < 32; ++k) {
              int p = j + 4*k;
              float w_ = wmat[lbuf][row][p];
              float4 tg = stgt[p];
              e0 += w_*tg.x; e1 += w_*tg.y; e2 += w_*tg.z; ew += w_;
            }
            e0 += __shfl_down(e0, 2, 4); e1 += __shfl_down(e1, 2, 4);
            e2 += __shfl_down(e2, 2, 4); ew += __shfl_down(ew, 2, 4);
            e0 += __shfl_down(e0, 1, 4); e1 += __shfl_down(e1, 1, 4);
            e2 += __shfl_down(e2, 1, 4); ew += __shfl_down(ew, 1, 4);
            if (j == 0) {
              int idx = p0 + lc0 + row;
              pgid[blk*PG + idx] = __float_as_int(recB[lc0+row].z);
              pval[blk*PG + idx] = make_float4(e0, e1, e2, ew);
            }
          }
        }
        __syncthreads();
      }
    }

    if (t < 128) {
      out[((b*3+0)*HI + yi)*WI + xi] = a0 + T * bg[b*3+0];
      out[((b*3+1)*HI + yi)*WI + xi] = a1 + T * bg[b*3+1];
      out[((b*3+2)*HI + yi)*WI + xi] = a2 + T * bg[b*3+2];
      out[OFF_ALPHA + (b*HI + yi)*WI + xi] = 1.0f - T;
    }

    __syncthreads();
    if (t == 0) {
      __threadfence();
      atomicExch(&tileflags[blk], MAGIC_HI | (unsigned long long)total);
    }
    return;
  }

  // ==================== reducer block ====================
  const int r = blk - NT2;                 // 0..15
  const int batch = r >> 3, seg = r & 7;   // owns gaussians [seg*128, +128)

  if (t < 128) {
    int e_own = (batch<<10) + seg*128 + t;
    PC g = proj_cull(e_own, means, opac, scales, rots, vm, pm);
    out[OFF_RADII + e_own] = g.radii;
  }

  float* acc = &wmat[0][0][0];             // 128*4 floats
  for (int i = t; i < 128*4; i += 256) acc[i] = 0.f;

  if (t < 128) {
    unsigned long long v;
    do { v = atomicAdd(&tileflags[batch*TPB + t], 0ull);
         if ((v & MASK_HI) != MAGIC_HI) __builtin_amdgcn_s_sleep(1);
    } while ((v & MASK_HI) != MAGIC_HI);
    scnt[t] = (int)(v & 0xFFFFull);
  }
  __syncthreads();
  __threadfence();

  if (t == 0) {
    int s = 0;
    for (int i = 0; i < TPB; ++i) { soff[i] = s; s += scnt[i]; }
    soff[TPB] = s;
  }
  __syncthreads();
  int E = soff[TPB];

  for (int idx = t; idx < E; idx += 256) {
    int lo = 0, hi = TPB-1;
    while (lo < hi) { int mid = (lo+hi+1) >> 1; if (soff[mid] <= idx) lo = mid; else hi = mid-1; }
    int tb = batch*TPB + lo;
    int j = idx - soff[lo];
    int gi = pgid[tb*PG + j];
    if ((gi >> 7) == seg) {
      float4 v = pval[tb*PG + j];
      int s = gi & 127;
      atomicAdd(&acc[s*4+0], v.x);
      atomicAdd(&acc[s*4+1], v.y);
      atomicAdd(&acc[s*4+2], v.z);
      atomicAdd(&acc[s*4+3], v.w);
    }
  }
  __syncthreads();

  if (t < 128) {
    int e_own = (batch<<10) + seg*128 + t;
    out[OFF_ESTC + e_own*3 + 0] = acc[t*4+0];
    out[OFF_ESTC + e_own*3 + 1] = acc[t*4+1];
    out[OFF_ESTC + e_own*3 + 2] = acc[t*4+2];
    out[OFF_ESTW + e_own]       = acc[t*4+3];
  }
}

extern "C" void kernel_launch(void* const* d_in, const int* in_sizes, int n_in,
                              void* d_out, int out_size, void* d_ws, size_t ws_size,
                              hipStream_t stream) {
  const float* means  = (const float*)d_in[0];
  const float* sh     = (const float*)d_in[1];
  const float* opac   = (const float*)d_in[2];
  const float* scales = (const float*)d_in[3];
  const float* rots   = (const float*)d_in[4];
  const float* target = (const float*)d_in[5];
  const float* bg     = (const float*)d_in[6];
  const float* vm     = (const float*)d_in[7];
  const float* pm     = (const float*)d_in[8];
  const float* campos = (const float*)d_in[9];
  float* out = (float*)d_out;

  float4* pval = (float4*)d_ws;                                       // 4 MB
  int* pgid = (int*)(pval + NT2*PG);                                  // 1 MB
  unsigned long long* tileflags = (unsigned long long*)(pgid + NT2*PG); // 2 KB

  fused_kernel<<<NT2 + NRED, 256, 0, stream>>>(
      means, sh, opac, scales, rots, vm, pm, campos, target, bg,
      pval, pgid, tileflags, out);
}

// Round 11
// 22.702 us; speedup vs baseline: 1.2270x; 1.1889x over previous
//
#include <hip/hip_runtime.h>
#include <math.h>

#define HI 128
#define WI 128
#define BB 2
#define PG 1024
#define NE (BB*PG)
#define TPB 64             /* tiles per batch: 8x8 grid of 16x16 px */
#define NTILES (BB*TPB)    /* 128 tile blocks */
#define NRED 32            /* 2 batches x 16 segments of 64 gaussians */
#define MAGIC_HI  0xFEEDFACECAFE0000ULL
#define MASK_HI   0xFFFFFFFFFFFF0000ULL

#define OFF_ALPHA (BB*3*HI*WI)            /* 98304  */
#define OFF_ESTC  (OFF_ALPHA + BB*HI*WI)  /* 131072 */
#define OFF_ESTW  (OFF_ESTC + BB*PG*3)    /* 137216 */
#define OFF_RADII (OFF_ESTW + BB*PG)      /* 139264 */

struct PC {
  float px, py, ex, ey;
  float A, B, C, op;
  unsigned key;
  float radii;
};

// Shared core: computes c00,c01,c11,depth,px,py,op,tau,valid.
#define PROJ_CORE(e)                                                        \
  float mx = means[(e)*3+0], my = means[(e)*3+1], mz = means[(e)*3+2];      \
  float hom0 = pm[0]*mx + pm[1]*my + pm[2]*mz + pm[3];                      \
  float hom1 = pm[4]*mx + pm[5]*my + pm[6]*mz + pm[7];                      \
  float hom3 = pm[12]*mx + pm[13]*my + pm[14]*mz + pm[15];                  \
  float p_w  = 1.0f / (hom3 + 1e-7f);                                       \
  float pp0 = hom0 * p_w, pp1 = hom1 * p_w;                                 \
  float pv0   = vm[0]*mx + vm[1]*my + vm[2]*mz  + vm[3];                    \
  float pv1   = vm[4]*mx + vm[5]*my + vm[6]*mz  + vm[7];                    \
  float depth = vm[8]*mx + vm[9]*my + vm[10]*mz + vm[11];                   \
  float qr = rots[(e)*4+0], qx = rots[(e)*4+1], qy = rots[(e)*4+2], qz = rots[(e)*4+3]; \
  float qn = sqrtf(qr*qr + qx*qx + qy*qy + qz*qz);                          \
  qr /= qn; qx /= qn; qy /= qn; qz /= qn;                                   \
  float R00 = 1.0f-2.0f*(qy*qy+qz*qz), R01 = 2.0f*(qx*qy-qr*qz), R02 = 2.0f*(qx*qz+qr*qy); \
  float R10 = 2.0f*(qx*qy+qr*qz), R11 = 1.0f-2.0f*(qx*qx+qz*qz), R12 = 2.0f*(qy*qz-qr*qx); \
  float R20 = 2.0f*(qx*qz-qr*qy), R21 = 2.0f*(qy*qz+qr*qx), R22 = 1.0f-2.0f*(qx*qx+qy*qy); \
  float s0 = scales[(e)*3+0], s1 = scales[(e)*3+1], s2 = scales[(e)*3+2];   \
  float M00=R00*s0, M01=R01*s1, M02=R02*s2;                                 \
  float M10=R10*s0, M11=R11*s1, M12=R12*s2;                                 \
  float M20=R20*s0, M21=R21*s1, M22=R22*s2;                                 \
  float S00 = M00*M00+M01*M01+M02*M02;                                      \
  float S01 = M00*M10+M01*M11+M02*M12;                                      \
  float S02 = M00*M20+M01*M21+M02*M22;                                      \
  float S11 = M10*M10+M11*M11+M12*M12;                                      \
  float S12 = M10*M20+M11*M21+M12*M22;                                      \
  float S22 = M20*M20+M21*M21+M22*M22;                                      \
  float tz = depth;                                                         \
  float txc = fminf(fmaxf(pv0/tz, -0.65f), 0.65f) * tz;                     \
  float tyc = fminf(fmaxf(pv1/tz, -0.65f), 0.65f) * tz;                     \
  float J00 = 128.0f/tz,  J02 = -128.0f*txc/(tz*tz);                        \
  float J11 = 128.0f/tz,  J12 = -128.0f*tyc/(tz*tz);                        \
  float T00 = J00*vm[0] + J02*vm[8];                                        \
  float T01 = J00*vm[1] + J02*vm[9];                                        \
  float T02 = J00*vm[2] + J02*vm[10];                                       \
  float T10 = J11*vm[4] + J12*vm[8];                                        \
  float T11 = J11*vm[5] + J12*vm[9];                                        \
  float T12 = J11*vm[6] + J12*vm[10];                                       \
  float TS00 = T00*S00 + T01*S01 + T02*S02;                                 \
  float TS01 = T00*S01 + T01*S11 + T02*S12;                                 \
  float TS02 = T00*S02 + T01*S12 + T02*S22;                                 \
  float TS10 = T10*S00 + T11*S01 + T12*S02;                                 \
  float TS11 = T10*S01 + T11*S11 + T12*S12;                                 \
  float TS12 = T10*S02 + T11*S12 + T12*S22;                                 \
  float c00 = TS00*T00 + TS01*T01 + TS02*T02 + 0.3f;                        \
  float c01 = TS00*T10 + TS01*T11 + TS02*T12;                               \
  float c11 = TS10*T10 + TS11*T11 + TS12*T12 + 0.3f;                        \
  float det = c00*c11 - c01*c01;                                            \
  bool valid = (depth > 0.2f) && (det > 1e-12f);                            \
  float opv = opac[(e)];                                                    \
  float tau = logf(255.0f * opv);                                           \
  bool rok = valid && (tau > 0.0f);

// Lite: cull rect + sort key only (no conic/radii).
__device__ __forceinline__ void cull_lite(int e,
    const float* __restrict__ means, const float* __restrict__ opac,
    const float* __restrict__ scales, const float* __restrict__ rots,
    const float* __restrict__ vm, const float* __restrict__ pm,
    float& px, float& py, float& ex, float& ey, unsigned& key)
{
  PROJ_CORE(e)
  px = ((pp0 + 1.0f)*WI - 1.0f)*0.5f;
  py = ((pp1 + 1.0f)*HI - 1.0f)*0.5f;
  ex = rok ? sqrtf(2.0f*tau*c00) + 0.02f : -1e9f;
  ey = rok ? sqrtf(2.0f*tau*c11) + 0.02f : -1e9f;
  unsigned u = __float_as_uint(depth);
  key = (u >> 31) ? ~u : (u | 0x80000000u);
  (void)valid; (void)opv; (void)c01; (void)det;
}

__device__ __forceinline__ PC proj_cull(int e,
    const float* __restrict__ means, const float* __restrict__ opac,
    const float* __restrict__ scales, const float* __restrict__ rots,
    const float* __restrict__ vm, const float* __restrict__ pm)
{
  PC o;
  PROJ_CORE(e)
  float inv_det = 1.0f / (det > 1e-12f ? det : 1.0f);
  o.A =  c11 * inv_det;
  o.B = -c01 * inv_det;
  o.C =  c00 * inv_det;
  float mid = 0.5f * (c00 + c11);
  float lam = mid + sqrtf(fmaxf(mid*mid - det, 0.1f));
  o.radii = valid ? ceilf(3.0f * sqrtf(lam)) : 0.0f;
  o.px = ((pp0 + 1.0f)*WI - 1.0f)*0.5f;
  o.py = ((pp1 + 1.0f)*HI - 1.0f)*0.5f;
  o.op = opv;
  o.ex = rok ? sqrtf(2.0f*tau*c00) + 0.02f : -1e9f;
  o.ey = rok ? sqrtf(2.0f*tau*c11) + 0.02f : -1e9f;
  unsigned u = __float_as_uint(depth);
  o.key = (u >> 31) ? ~u : (u | 0x80000000u);
  return o;
}

__device__ __forceinline__ void sh_color(int e,
    const float* __restrict__ sh, const float* __restrict__ means,
    const float* __restrict__ campos, float col[3])
{
  float mx = means[e*3+0], my = means[e*3+1], mz = means[e*3+2];
  float dxr = mx - campos[0], dyr = my - campos[1], dzr = mz - campos[2];
  float dn = sqrtf(dxr*dxr + dyr*dyr + dzr*dzr);
  float x = dxr/dn, y = dyr/dn, z = dzr/dn;
  float xx=x*x, yy=y*y, zz=z*z, xy=x*y, yz=y*z, xz=x*z;
  const float* S = sh + e*48;
  #pragma unroll
  for (int c = 0; c < 3; ++c) {
    float r = 0.28209479177387814f * S[0+c];
    r -= 0.4886025119029199f * y * S[3+c];
    r += 0.4886025119029199f * z * S[6+c];
    r -= 0.4886025119029199f * x * S[9+c];
    r += 1.0925484305920792f  * xy * S[12+c];
    r += -1.0925484305920792f * yz * S[15+c];
    r += 0.31539156525252005f * (2.0f*zz-xx-yy) * S[18+c];
    r += -1.0925484305920792f * xz * S[21+c];
    r += 0.5462742152960396f  * (xx-yy) * S[24+c];
    r += -0.5900435899266435f * y * (3.0f*xx-yy) * S[27+c];
    r += 2.890611442640554f   * xy * z * S[30+c];
    r += -0.4570457994644658f * y * (4.0f*zz-xx-yy) * S[33+c];
    r += 0.3731763325901154f  * z * (2.0f*zz-3.0f*xx-3.0f*yy) * S[36+c];
    r += -0.4570457994644658f * x * (4.0f*zz-xx-yy) * S[39+c];
    r += 1.445305721320277f   * z * (xx-yy) * S[42+c];
    r += -0.5900435899266435f * x * (xx-3.0f*yy) * S[45+c];
    col[c] = fmaxf(r + 0.5f, 0.0f);
  }
}

__global__ __launch_bounds__(256) void fused_kernel(
    const float* __restrict__ means, const float* __restrict__ sh,
    const float* __restrict__ opac, const float* __restrict__ scales,
    const float* __restrict__ rots, const float* __restrict__ vm,
    const float* __restrict__ pm, const float* __restrict__ campos,
    const float* __restrict__ target, const float* __restrict__ bg,
    float4* __restrict__ pval, int* __restrict__ pgid,
    unsigned long long* __restrict__ tileflags,
    float* __restrict__ out)
{
  const int t = threadIdx.x;
  const int wv = t >> 6, ln = t & 63;
  const int blk = blockIdx.x;

  __shared__ unsigned long long skey[PG];
  __shared__ float4 recA[256], recB[256], colC[256], stgt[256];
  __shared__ float  wmat[32][264];
  __shared__ int    wcnt[4];
  __shared__ int    scnt[64], soff[65];

  if (blk < NTILES) {
    // ==================== tile block: 16x16 px ====================
    const int b = blk >> 6, tile = blk & 63;
    const int tx0i = (tile & 7) * 16, ty0i = (tile >> 3) * 16;
    const int xi = tx0i + (t & 15), yi = ty0i + (t >> 4);
    const float fxp = (float)xi, fyp = (float)yi;
    const float rx0 = (float)tx0i, ry0 = (float)ty0i;

    stgt[t] = make_float4(target[((b*3+0)*HI + yi)*WI + xi],
                          target[((b*3+1)*HI + yi)*WI + xi],
                          target[((b*3+2)*HI + yi)*WI + xi], 1.0f);

    // scan: 4 gaussians per thread, ballot-compacted per wave
    int cnt = 0;
    unsigned long long kbuf[4]; int kok = 0;
    for (int k = 0; k < 4; ++k) {
      int ci = wv*256 + k*64 + ln;
      float px, py, ex, ey; unsigned key;
      cull_lite((b<<10)+ci, means, opac, scales, rots, vm, pm, px, py, ex, ey, key);
      bool ok = (px + ex >= rx0) && (px - ex <= rx0 + 15.0f)
             && (py + ey >= ry0) && (py - ey <= ry0 + 15.0f);
      unsigned long long m = __ballot(ok);
      if (ok) {
        kbuf[kok] = (((unsigned long long)key) << 10) | (unsigned)ci;
        // position within this wave's running compact region
        int pos = cnt + __popcll(m & ((1ull << ln) - 1ull));
        skey[wv*256 + pos] = kbuf[kok];
        ++kok;
      }
      cnt += __popcll(m);
    }
    if (ln == 0) wcnt[wv] = cnt;
    __syncthreads();
    int c0_ = wcnt[0], c1_ = wcnt[1], c2_ = wcnt[2], c3_ = wcnt[3];
    int total = c0_ + c1_ + c2_ + c3_;
    int off = (wv>0?c0_:0) + (wv>1?c1_:0) + (wv>2?c2_:0);
    // compact waves' regions together (dest <= src per wave; lockstep safe)
    for (int i = ln; i < cnt; i += 64) {
      unsigned long long v = skey[wv*256 + i];
      skey[off + i] = v;
    }
    __syncthreads();

    // sort survivors by (depth,idx)
    if (total > 1) {
      if (total <= 64) {
        if (t < 64) {
          unsigned long long v = (t < total) ? skey[t] : ~0ull;
          #pragma unroll
          for (int k = 2; k <= 64; k <<= 1) {
            bool dirAsc = ((t & k) == 0);
            #pragma unroll
            for (int j = k >> 1; j > 0; j >>= 1) {
              unsigned long long o = __shfl_xor(v, j, 64);
              bool takeMin = (((t & j) == 0) == dirAsc);
              bool less = v < o;
              v = (takeMin == less) ? v : o;
            }
          }
          if (t < total) skey[t] = v;
        }
        __syncthreads();
      } else {
        int M = 64; while (M < total) M <<= 1;
        for (int i = total + t; i < M; i += 256) skey[i] = ~0ull;
        __syncthreads();
        for (int k = 2; k <= M; k <<= 1)
          for (int j = k >> 1; j > 0; j >>= 1) {
            for (int base = t; base < M; base += 256) {
              int ixj = base ^ j;
              if (ixj > base) {
                unsigned long long a = skey[base], q = skey[ixj];
                bool up = ((base & k) == 0);
                if ((a > q) == up) { skey[base] = q; skey[ixj] = a; }
              }
            }
            __syncthreads();
          }
      }
    }

    float T = 1.0f, a0 = 0.f, a1 = 0.f, a2 = 0.f;

    for (int p0 = 0; p0 < total; p0 += 256) {
      int lim = min(256, total - p0);
      if (p0 + t < total) {
        int gi = (int)(skey[p0 + t] & 1023u);
        int e = (b<<10) + gi;
        PC r = proj_cull(e, means, opac, scales, rots, vm, pm);
        float col[3]; sh_color(e, sh, means, campos, col);
        recA[t] = make_float4(r.px, r.py, r.A, r.B);
        recB[t] = make_float4(r.C, r.op, __int_as_float(gi), 0.f);
        colC[t] = make_float4(col[0], col[1], col[2], 0.f);
      }
      __syncthreads();

      for (int c0 = 0; c0 < lim; c0 += 32) {
        int cc = min(32, lim - c0);
        for (int i = 0; i < cc; ++i) {
          float4 qa = recA[c0+i], qb = recB[c0+i], qc = colC[c0+i];
          float dx = qa.x - fxp, dy = qa.y - fyp;
          float power = -0.5f*(qa.z*dx*dx + qb.x*dy*dy) - qa.w*dx*dy;
          float alpha = fminf(0.99f, qb.y * __expf(power));
          bool keep = (power <= 0.0f) && (alpha >= (1.0f/255.0f));
          float w_ = keep ? alpha * T : 0.0f;
          a0 += w_*qc.x; a1 += w_*qc.y; a2 += w_*qc.z;
          T -= w_;
          wmat[i][t] = w_;
        }
        __syncthreads();
        int row = t >> 3, j = t & 7;
        if (row < cc) {
          float e0=0.f, e1=0.f, e2=0.f, ew=0.f;
          #pragma unroll 8
          for (int k = 0; k < 32; ++k) {
            int p = j + 8*k;
            float w_ = wmat[row][p];
            float4 tg = stgt[p];
            e0 += w_*tg.x; e1 += w_*tg.y; e2 += w_*tg.z; ew += w_;
          }
          #pragma unroll
          for (int o = 4; o; o >>= 1) {
            e0 += __shfl_down(e0, o, 8); e1 += __shfl_down(e1, o, 8);
            e2 += __shfl_down(e2, o, 8); ew += __shfl_down(ew, o, 8);
          }
          if (j == 0) {
            int idx = p0 + c0 + row;
            pgid[blk*PG + idx] = __float_as_int(recB[c0+row].z);
            pval[blk*PG + idx] = make_float4(e0, e1, e2, ew);
          }
        }
        __syncthreads();
      }
    }

    out[((b*3+0)*HI + yi)*WI + xi] = a0 + T * bg[b*3+0];
    out[((b*3+1)*HI + yi)*WI + xi] = a1 + T * bg[b*3+1];
    out[((b*3+2)*HI + yi)*WI + xi] = a2 + T * bg[b*3+2];
    out[OFF_ALPHA + (b*HI + yi)*WI + xi] = 1.0f - T;

    __syncthreads();
    if (t == 0) {
      __threadfence();
      atomicExch(&tileflags[blk], MAGIC_HI | (unsigned long long)total);
    }
    return;
  }

  // ==================== reducer block ====================
  const int r = blk - NTILES;               // 0..31
  const int batch = r >> 4, seg = r & 15;   // owns gaussians [seg*64, +64)

  if (t < 64) {
    int e_own = (batch<<10) + seg*64 + t;
    PC g = proj_cull(e_own, means, opac, scales, rots, vm, pm);
    out[OFF_RADII + e_own] = g.radii;
  }

  float* acc = &wmat[0][0];                 // 64*4 floats
  for (int i = t; i < 64*4; i += 256) acc[i] = 0.f;

  if (t < 64) {
    unsigned long long v;
    do { v = atomicAdd(&tileflags[batch*TPB + t], 0ull);
         if ((v & MASK_HI) != MAGIC_HI) __builtin_amdgcn_s_sleep(2);
    } while ((v & MASK_HI) != MAGIC_HI);
    scnt[t] = (int)(v & 0xFFFFull);
  }
  __syncthreads();
  __threadfence();

  if (t == 0) {
    int s = 0;
    for (int i = 0; i < TPB; ++i) { soff[i] = s; s += scnt[i]; }
    soff[TPB] = s;
  }
  __syncthreads();
  int E = soff[TPB];

  for (int idx = t; idx < E; idx += 256) {
    int lo = 0, hi = TPB-1;
    while (lo < hi) { int mid = (lo+hi+1) >> 1; if (soff[mid] <= idx) lo = mid; else hi = mid-1; }
    int tb = batch*TPB + lo;
    int j = idx - soff[lo];
    int gi = pgid[tb*PG + j];
    if ((gi >> 6) == seg) {
      float4 v = pval[tb*PG + j];
      int s = gi & 63;
      atomicAdd(&acc[s*4+0], v.x);
      atomicAdd(&acc[s*4+1], v.y);
      atomicAdd(&acc[s*4+2], v.z);
      atomicAdd(&acc[s*4+3], v.w);
    }
  }
  __syncthreads();

  if (t < 64) {
    int e_own = (batch<<10) + seg*64 + t;
    out[OFF_ESTC + e_own*3 + 0] = acc[t*4+0];
    out[OFF_ESTC + e_own*3 + 1] = acc[t*4+1];
    out[OFF_ESTC + e_own*3 + 2] = acc[t*4+2];
    out[OFF_ESTW + e_own]       = acc[t*4+3];
  }
}

extern "C" void kernel_launch(void* const* d_in, const int* in_sizes, int n_in,
                              void* d_out, int out_size, void* d_ws, size_t ws_size,
                              hipStream_t stream) {
  const float* means  = (const float*)d_in[0];
  const float* sh     = (const float*)d_in[1];
  const float* opac   = (const float*)d_in[2];
  const float* scales = (const float*)d_in[3];
  const float* rots   = (const float*)d_in[4];
  const float* target = (const float*)d_in[5];
  const float* bg     = (const float*)d_in[6];
  const float* vm     = (const float*)d_in[7];
  const float* pm     = (const float*)d_in[8];
  const float* campos = (const float*)d_in[9];
  float* out = (float*)d_out;

  float4* pval = (float4*)d_ws;                                         // 2 MB
  int* pgid = (int*)(pval + NTILES*PG);                                 // 512 KB
  unsigned long long* tileflags = (unsigned long long*)(pgid + NTILES*PG); // 1 KB

  fused_kernel<<<NTILES + NRED, 256, 0, stream>>>(
      means, sh, opac, scales, rots, vm, pm, campos, target, bg,
      pval, pgid, tileflags, out);
}

// Round 12
// 21.542 us; speedup vs baseline: 1.2931x; 1.0539x over previous
//
#include <hip/hip_runtime.h>
#include <math.h>

#define HI 128
#define WI 128
#define BB 2
#define PG 1024
#define NE (BB*PG)
#define NTILES 128          /* 2 batches x 64 tiles of 16x16 */
#define NRED 16             /* 2 batches x 8 segments of 128 gaussians */
#define MAGIC_HI 0xFEEDFACECAFE0000ULL
#define MASK_HI  0xFFFFFFFFFFFF0000ULL

#define OFF_ALPHA (BB*3*HI*WI)            /* 98304  */
#define OFF_ESTC  (OFF_ALPHA + BB*HI*WI)  /* 131072 */
#define OFF_ESTW  (OFF_ESTC + BB*PG*3)    /* 137216 */
#define OFF_RADII (OFF_ESTW + BB*PG)      /* 139264 */

struct PC {
  float px, py, ex, ey;
  float A, B, C, op;
  unsigned key;
  float radii;
};

__device__ __forceinline__ PC proj_cull(int e,
    const float* __restrict__ means, const float* __restrict__ opac,
    const float* __restrict__ scales, const float* __restrict__ rots,
    const float* __restrict__ vm, const float* __restrict__ pm)
{
  PC o;
  float mx = means[e*3+0], my = means[e*3+1], mz = means[e*3+2];

  float hom0 = pm[0]*mx + pm[1]*my + pm[2]*mz + pm[3];
  float hom1 = pm[4]*mx + pm[5]*my + pm[6]*mz + pm[7];
  float hom3 = pm[12]*mx + pm[13]*my + pm[14]*mz + pm[15];
  float p_w  = 1.0f / (hom3 + 1e-7f);
  float pp0 = hom0 * p_w, pp1 = hom1 * p_w;

  float pv0   = vm[0]*mx + vm[1]*my + vm[2]*mz  + vm[3];
  float pv1   = vm[4]*mx + vm[5]*my + vm[6]*mz  + vm[7];
  float depth = vm[8]*mx + vm[9]*my + vm[10]*mz + vm[11];

  float qr = rots[e*4+0], qx = rots[e*4+1], qy = rots[e*4+2], qz = rots[e*4+3];
  float qn = sqrtf(qr*qr + qx*qx + qy*qy + qz*qz);
  qr /= qn; qx /= qn; qy /= qn; qz /= qn;
  float R00 = 1.0f-2.0f*(qy*qy+qz*qz), R01 = 2.0f*(qx*qy-qr*qz), R02 = 2.0f*(qx*qz+qr*qy);
  float R10 = 2.0f*(qx*qy+qr*qz), R11 = 1.0f-2.0f*(qx*qx+qz*qz), R12 = 2.0f*(qy*qz-qr*qx);
  float R20 = 2.0f*(qx*qz-qr*qy), R21 = 2.0f*(qy*qz+qr*qx), R22 = 1.0f-2.0f*(qx*qx+qy*qy);

  float s0 = scales[e*3+0], s1 = scales[e*3+1], s2 = scales[e*3+2];
  float M00=R00*s0, M01=R01*s1, M02=R02*s2;
  float M10=R10*s0, M11=R11*s1, M12=R12*s2;
  float M20=R20*s0, M21=R21*s1, M22=R22*s2;
  float S00 = M00*M00+M01*M01+M02*M02;
  float S01 = M00*M10+M01*M11+M02*M12;
  float S02 = M00*M20+M01*M21+M02*M22;
  float S11 = M10*M10+M11*M11+M12*M12;
  float S12 = M10*M20+M11*M21+M12*M22;
  float S22 = M20*M20+M21*M21+M22*M22;

  const float fx = 128.0f, fyc = 128.0f;
  float tz = depth;
  float txc = fminf(fmaxf(pv0/tz, -0.65f), 0.65f) * tz;
  float tyc = fminf(fmaxf(pv1/tz, -0.65f), 0.65f) * tz;
  float J00 = fx/tz,  J02 = -fx*txc/(tz*tz);
  float J11 = fyc/tz, J12 = -fyc*tyc/(tz*tz);

  float T00 = J00*vm[0] + J02*vm[8];
  float T01 = J00*vm[1] + J02*vm[9];
  float T02 = J00*vm[2] + J02*vm[10];
  float T10 = J11*vm[4] + J12*vm[8];
  float T11 = J11*vm[5] + J12*vm[9];
  float T12 = J11*vm[6] + J12*vm[10];

  float TS00 = T00*S00 + T01*S01 + T02*S02;
  float TS01 = T00*S01 + T01*S11 + T02*S12;
  float TS02 = T00*S02 + T01*S12 + T02*S22;
  float TS10 = T10*S00 + T11*S01 + T12*S02;
  float TS11 = T10*S01 + T11*S11 + T12*S12;
  float TS12 = T10*S02 + T11*S12 + T12*S22;

  float c00 = TS00*T00 + TS01*T01 + TS02*T02 + 0.3f;
  float c01 = TS00*T10 + TS01*T11 + TS02*T12;
  float c11 = TS10*T10 + TS11*T11 + TS12*T12 + 0.3f;

  float det = c00*c11 - c01*c01;
  bool valid = (depth > 0.2f) && (det > 1e-12f);
  float inv_det = 1.0f / (det > 1e-12f ? det : 1.0f);
  o.A =  c11 * inv_det;
  o.B = -c01 * inv_det;
  o.C =  c00 * inv_det;
  float mid = 0.5f * (c00 + c11);
  float lam = mid + sqrtf(fmaxf(mid*mid - det, 0.1f));
  o.radii = valid ? ceilf(3.0f * sqrtf(lam)) : 0.0f;

  o.px = ((pp0 + 1.0f)*WI - 1.0f)*0.5f;
  o.py = ((pp1 + 1.0f)*HI - 1.0f)*0.5f;

  float opv = opac[e];
  o.op = opv;
  float tau = logf(255.0f * opv);
  bool rok = valid && (tau > 0.0f);
  o.ex = rok ? sqrtf(2.0f*tau*c00) + 0.02f : -1e9f;
  o.ey = rok ? sqrtf(2.0f*tau*c11) + 0.02f : -1e9f;

  unsigned u = __float_as_uint(depth);
  o.key = (u >> 31) ? ~u : (u | 0x80000000u);
  return o;
}

__device__ __forceinline__ void sh_color(int e,
    const float* __restrict__ sh, const float* __restrict__ means,
    const float* __restrict__ campos, float col[3])
{
  float mx = means[e*3+0], my = means[e*3+1], mz = means[e*3+2];
  float dxr = mx - campos[0], dyr = my - campos[1], dzr = mz - campos[2];
  float dn = sqrtf(dxr*dxr + dyr*dyr + dzr*dzr);
  float x = dxr/dn, y = dyr/dn, z = dzr/dn;
  float xx=x*x, yy=y*y, zz=z*z, xy=x*y, yz=y*z, xz=x*z;
  const float* S = sh + e*48;
  #pragma unroll
  for (int c = 0; c < 3; ++c) {
    float r = 0.28209479177387814f * S[0+c];
    r -= 0.4886025119029199f * y * S[3+c];
    r += 0.4886025119029199f * z * S[6+c];
    r -= 0.4886025119029199f * x * S[9+c];
    r += 1.0925484305920792f  * xy * S[12+c];
    r += -1.0925484305920792f * yz * S[15+c];
    r += 0.31539156525252005f * (2.0f*zz-xx-yy) * S[18+c];
    r += -1.0925484305920792f * xz * S[21+c];
    r += 0.5462742152960396f  * (xx-yy) * S[24+c];
    r += -0.5900435899266435f * y * (3.0f*xx-yy) * S[27+c];
    r += 2.890611442640554f   * xy * z * S[30+c];
    r += -0.4570457994644658f * y * (4.0f*zz-xx-yy) * S[33+c];
    r += 0.3731763325901154f  * z * (2.0f*zz-3.0f*xx-3.0f*yy) * S[36+c];
    r += -0.4570457994644658f * x * (4.0f*zz-xx-yy) * S[39+c];
    r += 1.445305721320277f   * z * (xx-yy) * S[42+c];
    r += -0.5900435899266435f * x * (xx-3.0f*yy) * S[45+c];
    col[c] = fmaxf(r + 0.5f, 0.0f);
  }
}

__global__ __launch_bounds__(256) void fused_kernel(
    const float* __restrict__ means, const float* __restrict__ sh,
    const float* __restrict__ opac, const float* __restrict__ scales,
    const float* __restrict__ rots, const float* __restrict__ vm,
    const float* __restrict__ pm, const float* __restrict__ campos,
    const float* __restrict__ target, const float* __restrict__ bg,
    float4* __restrict__ pval, unsigned long long* __restrict__ flags,
    int* __restrict__ pgid, float* __restrict__ out)
{
  const int t = threadIdx.x;
  const int blk = blockIdx.x;

  __shared__ unsigned long long skey[PG];
  __shared__ float4 recA[256], recB[256], colC[256], stgt[256];
  __shared__ float  wmat[32][264];          /* tile: w matrix; reducer: acc */
  __shared__ int    scount;
  __shared__ int    scnt[64], soff[65];

  if (blk < NTILES) {
    // ==================== tile block ====================
    const int b = blk >> 6, tile = blk & 63;
    const int tx0i = (tile & 7) * 16, ty0i = (tile >> 3) * 16;
    const int xi = tx0i + (t & 15), yi = ty0i + (t >> 4);
    const float fxp = (float)xi, fyp = (float)yi;
    const float rx0 = (float)tx0i, ry0 = (float)ty0i;

    if (t == 0) scount = 0;
    stgt[t] = make_float4(target[((b*3+0)*HI + yi)*WI + xi],
                          target[((b*3+1)*HI + yi)*WI + xi],
                          target[((b*3+2)*HI + yi)*WI + xi], 1.0f);
    __syncthreads();

    for (int k = 0; k < 4; ++k) {
      int ci = k*256 + t;
      PC r = proj_cull((b<<10)+ci, means, opac, scales, rots, vm, pm);
      bool ok = (r.px + r.ex >= rx0) && (r.px - r.ex <= rx0 + 15.0f)
             && (r.py + r.ey >= ry0) && (r.py - r.ey <= ry0 + 15.0f);
      if (ok) {
        int pos = atomicAdd(&scount, 1);
        skey[pos] = (((unsigned long long)r.key) << 10) | (unsigned)ci;
      }
    }
    __syncthreads();
    int total = scount;

    if (total > 1) {
      if (total <= 64) {
        if (t < 64) {
          unsigned long long v = (t < total) ? skey[t] : ~0ull;
          #pragma unroll
          for (int k = 2; k <= 64; k <<= 1) {
            bool dirAsc = ((t & k) == 0);
            #pragma unroll
            for (int j = k >> 1; j > 0; j >>= 1) {
              unsigned long long o = __shfl_xor(v, j, 64);
              bool takeMin = (((t & j) == 0) == dirAsc);
              bool less = v < o;
              v = (takeMin == less) ? v : o;
            }
          }
          if (t < total) skey[t] = v;
        }
        __syncthreads();
      } else {
        int M = 64; while (M < total) M <<= 1;
        for (int i = total + t; i < M; i += 256) skey[i] = ~0ull;
        __syncthreads();
        for (int k = 2; k <= M; k <<= 1)
          for (int j = k >> 1; j > 0; j >>= 1) {
            for (int base = t; base < M; base += 256) {
              int ixj = base ^ j;
              if (ixj > base) {
                unsigned long long a = skey[base], q = skey[ixj];
                bool up = ((base & k) == 0);
                if ((a > q) == up) { skey[base] = q; skey[ixj] = a; }
              }
            }
            __syncthreads();
          }
      }
    }

    float T = 1.0f, a0 = 0.f, a1 = 0.f, a2 = 0.f;

    for (int p0 = 0; p0 < total; p0 += 256) {
      int lim = min(256, total - p0);
      if (p0 + t < total) {
        int gi = (int)(skey[p0 + t] & 1023u);
        int e = (b<<10) + gi;
        PC r = proj_cull(e, means, opac, scales, rots, vm, pm);
        float col[3]; sh_color(e, sh, means, campos, col);
        recA[t] = make_float4(r.px, r.py, r.A, r.B);
        recB[t] = make_float4(r.C, r.op, __int_as_float(gi), 0.f);
        colC[t] = make_float4(col[0], col[1], col[2], 0.f);
      }
      __syncthreads();

      for (int c0 = 0; c0 < lim; c0 += 32) {
        int cc = min(32, lim - c0);
        for (int i = 0; i < cc; ++i) {
          float4 qa = recA[c0+i], qb = recB[c0+i], qc = colC[c0+i];
          float dx = qa.x - fxp, dy = qa.y - fyp;
          float power = -0.5f*(qa.z*dx*dx + qb.x*dy*dy) - qa.w*dx*dy;
          float alpha = fminf(0.99f, qb.y * __expf(power));
          bool keep = (power <= 0.0f) && (alpha >= (1.0f/255.0f));
          float w_ = keep ? alpha * T : 0.0f;
          a0 += w_*qc.x; a1 += w_*qc.y; a2 += w_*qc.z;
          T -= w_;
          wmat[i][t] = w_;
        }
        __syncthreads();
        int row = t >> 3, j = t & 7;
        if (row < cc) {
          float e0=0.f, e1=0.f, e2=0.f, ew=0.f;
          #pragma unroll 8
          for (int k = 0; k < 32; ++k) {
            int p = j + 8*k;
            float w_ = wmat[row][p];
            float4 tg = stgt[p];
            e0 += w_*tg.x; e1 += w_*tg.y; e2 += w_*tg.z; ew += w_;
          }
          #pragma unroll
          for (int o = 4; o; o >>= 1) {
            e0 += __shfl_down(e0, o, 8); e1 += __shfl_down(e1, o, 8);
            e2 += __shfl_down(e2, o, 8); ew += __shfl_down(ew, o, 8);
          }
          if (j == 0) {
            int idx = p0 + c0 + row;
            pgid[blk*PG + idx] = __float_as_int(recB[c0+row].z);
            pval[blk*PG + idx] = make_float4(e0, e1, e2, ew);
          }
        }
        __syncthreads();
      }
    }

    out[((b*3+0)*HI + yi)*WI + xi] = a0 + T * bg[b*3+0];
    out[((b*3+1)*HI + yi)*WI + xi] = a1 + T * bg[b*3+1];
    out[((b*3+2)*HI + yi)*WI + xi] = a2 + T * bg[b*3+2];
    out[OFF_ALPHA + (b*HI + yi)*WI + xi] = 1.0f - T;

    __syncthreads();
    if (t == 0) {
      __threadfence();
      atomicExch(&flags[blk], MAGIC_HI | (unsigned long long)total);
    }
    return;
  }

  // ==================== reducer block ====================
  const int r = blk - NTILES;              // 0..15
  const int batch = r >> 3, seg = r & 7;   // owns gaussians [seg*128, seg*128+128)

  if (t < 128) {
    int e_own = (batch<<10) + seg*128 + t;
    PC g = proj_cull(e_own, means, opac, scales, rots, vm, pm);
    out[OFF_RADII + e_own] = g.radii;
  }

  float* acc = &wmat[0][0];                // 128*4 floats
  for (int i = t; i < 128*4; i += 256) acc[i] = 0.f;

  if (t < 64) {
    unsigned long long v;
    do { v = atomicAdd(&flags[batch*64 + t], 0ull);
         if ((v & MASK_HI) != MAGIC_HI) __builtin_amdgcn_s_sleep(1);
    } while ((v & MASK_HI) != MAGIC_HI);
    scnt[t] = (int)(v & 0xFFFFull);
  }
  __syncthreads();
  __threadfence();

  if (t == 0) {
    int s = 0;
    for (int i = 0; i < 64; ++i) { soff[i] = s; s += scnt[i]; }
    soff[64] = s;
  }
  __syncthreads();
  int E = soff[64];

  for (int idx = t; idx < E; idx += 256) {
    int lo = 0, hi = 63;
    while (lo < hi) { int mid = (lo+hi+1) >> 1; if (soff[mid] <= idx) lo = mid; else hi = mid-1; }
    int tb = batch*64 + lo;
    int j = idx - soff[lo];
    int gi = pgid[tb*PG + j];
    if ((gi >> 7) == seg) {
      float4 v = pval[tb*PG + j];
      int s = gi & 127;
      atomicAdd(&acc[s*4+0], v.x);
      atomicAdd(&acc[s*4+1], v.y);
      atomicAdd(&acc[s*4+2], v.z);
      atomicAdd(&acc[s*4+3], v.w);
    }
  }
  __syncthreads();

  if (t < 128) {
    int e_own = (batch<<10) + seg*128 + t;
    out[OFF_ESTC + e_own*3 + 0] = acc[t*4+0];
    out[OFF_ESTC + e_own*3 + 1] = acc[t*4+1];
    out[OFF_ESTC + e_own*3 + 2] = acc[t*4+2];
    out[OFF_ESTW + e_own]       = acc[t*4+3];
  }
}

extern "C" void kernel_launch(void* const* d_in, const int* in_sizes, int n_in,
                              void* d_out, int out_size, void* d_ws, size_t ws_size,
                              hipStream_t stream) {
  const float* means  = (const float*)d_in[0];
  const float* sh     = (const float*)d_in[1];
  const float* opac   = (const float*)d_in[2];
  const float* scales = (const float*)d_in[3];
  const float* rots   = (const float*)d_in[4];
  const float* target = (const float*)d_in[5];
  const float* bg     = (const float*)d_in[6];
  const float* vm     = (const float*)d_in[7];
  const float* pm     = (const float*)d_in[8];
  const float* campos = (const float*)d_in[9];
  float* out = (float*)d_out;

  float4* pval = (float4*)d_ws;                                        // 2 MB
  unsigned long long* flags = (unsigned long long*)(pval + NTILES*PG); // 1 KB
  int* pgid = (int*)(flags + NTILES);                                  // 512 KB

  fused_kernel<<<NTILES + NRED, 256, 0, stream>>>(
      means, sh, opac, scales, rots, vm, pm, campos, target, bg,
      pval, flags, pgid, out);
}

// Round 13
// 20.301 us; speedup vs baseline: 1.3722x; 1.0611x over previous
//
#include <hip/hip_runtime.h>
#include <math.h>

#define HI 128
#define WI 128
#define BB 2
#define PG 1024
#define NE (BB*PG)
#define NTILES 128          /* 2 batches x 64 tiles of 16x16 */
#define NRED 16             /* 2 batches x 8 segments of 128 gaussians */
#define MAGIC_HI 0xFEEDFACECAFE0000ULL
#define MASK_HI  0xFFFFFFFFFFFF0000ULL

#define OFF_ALPHA (BB*3*HI*WI)            /* 98304  */
#define OFF_ESTC  (OFF_ALPHA + BB*HI*WI)  /* 131072 */
#define OFF_ESTW  (OFF_ESTC + BB*PG*3)    /* 137216 */
#define OFF_RADII (OFF_ESTW + BB*PG)      /* 139264 */

struct PC {
  float px, py, ex, ey;
  float A, B, C, op;
  unsigned key;
  float radii;
};

__device__ __forceinline__ PC proj_cull(int e,
    const float* __restrict__ means, const float* __restrict__ opac,
    const float* __restrict__ scales, const float* __restrict__ rots,
    const float* __restrict__ vm, const float* __restrict__ pm)
{
  PC o;
  float mx = means[e*3+0], my = means[e*3+1], mz = means[e*3+2];

  float hom0 = pm[0]*mx + pm[1]*my + pm[2]*mz + pm[3];
  float hom1 = pm[4]*mx + pm[5]*my + pm[6]*mz + pm[7];
  float hom3 = pm[12]*mx + pm[13]*my + pm[14]*mz + pm[15];
  float p_w  = 1.0f / (hom3 + 1e-7f);
  float pp0 = hom0 * p_w, pp1 = hom1 * p_w;

  float pv0   = vm[0]*mx + vm[1]*my + vm[2]*mz  + vm[3];
  float pv1   = vm[4]*mx + vm[5]*my + vm[6]*mz  + vm[7];
  float depth = vm[8]*mx + vm[9]*my + vm[10]*mz + vm[11];

  float qr = rots[e*4+0], qx = rots[e*4+1], qy = rots[e*4+2], qz = rots[e*4+3];
  float qn = sqrtf(qr*qr + qx*qx + qy*qy + qz*qz);
  qr /= qn; qx /= qn; qy /= qn; qz /= qn;
  float R00 = 1.0f-2.0f*(qy*qy+qz*qz), R01 = 2.0f*(qx*qy-qr*qz), R02 = 2.0f*(qx*qz+qr*qy);
  float R10 = 2.0f*(qx*qy+qr*qz), R11 = 1.0f-2.0f*(qx*qx+qz*qz), R12 = 2.0f*(qy*qz-qr*qx);
  float R20 = 2.0f*(qx*qz-qr*qy), R21 = 2.0f*(qy*qz+qr*qx), R22 = 1.0f-2.0f*(qx*qx+qy*qy);

  float s0 = scales[e*3+0], s1 = scales[e*3+1], s2 = scales[e*3+2];
  float M00=R00*s0, M01=R01*s1, M02=R02*s2;
  float M10=R10*s0, M11=R11*s1, M12=R12*s2;
  float M20=R20*s0, M21=R21*s1, M22=R22*s2;
  float S00 = M00*M00+M01*M01+M02*M02;
  float S01 = M00*M10+M01*M11+M02*M12;
  float S02 = M00*M20+M01*M21+M02*M22;
  float S11 = M10*M10+M11*M11+M12*M12;
  float S12 = M10*M20+M11*M21+M12*M22;
  float S22 = M20*M20+M21*M21+M22*M22;

  const float fx = 128.0f, fyc = 128.0f;
  float tz = depth;
  float txc = fminf(fmaxf(pv0/tz, -0.65f), 0.65f) * tz;
  float tyc = fminf(fmaxf(pv1/tz, -0.65f), 0.65f) * tz;
  float J00 = fx/tz,  J02 = -fx*txc/(tz*tz);
  float J11 = fyc/tz, J12 = -fyc*tyc/(tz*tz);

  float T00 = J00*vm[0] + J02*vm[8];
  float T01 = J00*vm[1] + J02*vm[9];
  float T02 = J00*vm[2] + J02*vm[10];
  float T10 = J11*vm[4] + J12*vm[8];
  float T11 = J11*vm[5] + J12*vm[9];
  float T12 = J11*vm[6] + J12*vm[10];

  float TS00 = T00*S00 + T01*S01 + T02*S02;
  float TS01 = T00*S01 + T01*S11 + T02*S12;
  float TS02 = T00*S02 + T01*S12 + T02*S22;
  float TS10 = T10*S00 + T11*S01 + T12*S02;
  float TS11 = T10*S01 + T11*S11 + T12*S12;
  float TS12 = T10*S02 + T11*S12 + T12*S22;

  float c00 = TS00*T00 + TS01*T01 + TS02*T02 + 0.3f;
  float c01 = TS00*T10 + TS01*T11 + TS02*T12;
  float c11 = TS10*T10 + TS11*T11 + TS12*T12 + 0.3f;

  float det = c00*c11 - c01*c01;
  bool valid = (depth > 0.2f) && (det > 1e-12f);
  float inv_det = 1.0f / (det > 1e-12f ? det : 1.0f);
  o.A =  c11 * inv_det;
  o.B = -c01 * inv_det;
  o.C =  c00 * inv_det;
  float mid = 0.5f * (c00 + c11);
  float lam = mid + sqrtf(fmaxf(mid*mid - det, 0.1f));
  o.radii = valid ? ceilf(3.0f * sqrtf(lam)) : 0.0f;

  o.px = ((pp0 + 1.0f)*WI - 1.0f)*0.5f;
  o.py = ((pp1 + 1.0f)*HI - 1.0f)*0.5f;

  float opv = opac[e];
  o.op = opv;
  float tau = logf(255.0f * opv);
  bool rok = valid && (tau > 0.0f);
  o.ex = rok ? sqrtf(2.0f*tau*c00) + 0.02f : -1e9f;
  o.ey = rok ? sqrtf(2.0f*tau*c11) + 0.02f : -1e9f;

  unsigned u = __float_as_uint(depth);
  o.key = (u >> 31) ? ~u : (u | 0x80000000u);
  return o;
}

__device__ __forceinline__ void sh_color(int e,
    const float* __restrict__ sh, const float* __restrict__ means,
    const float* __restrict__ campos, float col[3])
{
  float mx = means[e*3+0], my = means[e*3+1], mz = means[e*3+2];
  float dxr = mx - campos[0], dyr = my - campos[1], dzr = mz - campos[2];
  float dn = sqrtf(dxr*dxr + dyr*dyr + dzr*dzr);
  float x = dxr/dn, y = dyr/dn, z = dzr/dn;
  float xx=x*x, yy=y*y, zz=z*z, xy=x*y, yz=y*z, xz=x*z;
  const float* S = sh + e*48;
  #pragma unroll
  for (int c = 0; c < 3; ++c) {
    float r = 0.28209479177387814f * S[0+c];
    r -= 0.4886025119029199f * y * S[3+c];
    r += 0.4886025119029199f * z * S[6+c];
    r -= 0.4886025119029199f * x * S[9+c];
    r += 1.0925484305920792f  * xy * S[12+c];
    r += -1.0925484305920792f * yz * S[15+c];
    r += 0.31539156525252005f * (2.0f*zz-xx-yy) * S[18+c];
    r += -1.0925484305920792f * xz * S[21+c];
    r += 0.5462742152960396f  * (xx-yy) * S[24+c];
    r += -0.5900435899266435f * y * (3.0f*xx-yy) * S[27+c];
    r += 2.890611442640554f   * xy * z * S[30+c];
    r += -0.4570457994644658f * y * (4.0f*zz-xx-yy) * S[33+c];
    r += 0.3731763325901154f  * z * (2.0f*zz-3.0f*xx-3.0f*yy) * S[36+c];
    r += -0.4570457994644658f * x * (4.0f*zz-xx-yy) * S[39+c];
    r += 1.445305721320277f   * z * (xx-yy) * S[42+c];
    r += -0.5900435899266435f * x * (xx-3.0f*yy) * S[45+c];
    col[c] = fmaxf(r + 0.5f, 0.0f);
  }
}

__global__ __launch_bounds__(512) void fused_kernel(
    const float* __restrict__ means, const float* __restrict__ sh,
    const float* __restrict__ opac, const float* __restrict__ scales,
    const float* __restrict__ rots, const float* __restrict__ vm,
    const float* __restrict__ pm, const float* __restrict__ campos,
    const float* __restrict__ target, const float* __restrict__ bg,
    float4* __restrict__ pval, unsigned long long* __restrict__ flags,
    int* __restrict__ pgid, float* __restrict__ out)
{
  const int t = threadIdx.x;
  const int blk = blockIdx.x;

  __shared__ unsigned long long skey[PG];
  __shared__ float4 recA[256], recB[256], colC[256], stgt[256];
  __shared__ float  wmat[32][264];          /* tile: w matrix; reducer: acc */
  __shared__ int    scount;
  __shared__ int    scnt[64], soff[65];

  if (blk < NTILES) {
    // ==================== tile block (512 thr, 256 px) ====================
    const int b = blk >> 6, tile = blk & 63;
    const int tx0i = (tile & 7) * 16, ty0i = (tile >> 3) * 16;
    const int xi = tx0i + (t & 15), yi = ty0i + ((t >> 4) & 15);
    const float fxp = (float)xi, fyp = (float)yi;
    const float rx0 = (float)tx0i, ry0 = (float)ty0i;

    if (t == 0) scount = 0;
    if (t < 256) {
      stgt[t] = make_float4(target[((b*3+0)*HI + yi)*WI + xi],
                            target[((b*3+1)*HI + yi)*WI + xi],
                            target[((b*3+2)*HI + yi)*WI + xi], 1.0f);
    }
    __syncthreads();

    // scan: 2 gaussians per thread (1024 total)
    for (int k = 0; k < 2; ++k) {
      int ci = k*512 + t;
      PC r = proj_cull((b<<10)+ci, means, opac, scales, rots, vm, pm);
      bool ok = (r.px + r.ex >= rx0) && (r.px - r.ex <= rx0 + 15.0f)
             && (r.py + r.ey >= ry0) && (r.py - r.ey <= ry0 + 15.0f);
      if (ok) {
        int pos = atomicAdd(&scount, 1);
        skey[pos] = (((unsigned long long)r.key) << 10) | (unsigned)ci;
      }
    }
    __syncthreads();
    int total = scount;

    if (total > 1) {
      if (total <= 64) {
        if (t < 64) {
          unsigned long long v = (t < total) ? skey[t] : ~0ull;
          #pragma unroll
          for (int k = 2; k <= 64; k <<= 1) {
            bool dirAsc = ((t & k) == 0);
            #pragma unroll
            for (int j = k >> 1; j > 0; j >>= 1) {
              unsigned long long o = __shfl_xor(v, j, 64);
              bool takeMin = (((t & j) == 0) == dirAsc);
              bool less = v < o;
              v = (takeMin == less) ? v : o;
            }
          }
          if (t < total) skey[t] = v;
        }
        __syncthreads();
      } else {
        int M = 64; while (M < total) M <<= 1;
        for (int i = total + t; i < M; i += 512) skey[i] = ~0ull;
        __syncthreads();
        for (int k = 2; k <= M; k <<= 1)
          for (int j = k >> 1; j > 0; j >>= 1) {
            for (int base = t; base < M; base += 512) {
              int ixj = base ^ j;
              if (ixj > base) {
                unsigned long long a = skey[base], q = skey[ixj];
                bool up = ((base & k) == 0);
                if ((a > q) == up) { skey[base] = q; skey[ixj] = a; }
              }
            }
            __syncthreads();
          }
      }
    }

    float T = 1.0f, a0 = 0.f, a1 = 0.f, a2 = 0.f;

    for (int p0 = 0; p0 < total; p0 += 256) {
      int lim = min(256, total - p0);
      // split stage: lower half does conic record, upper half does SH color
      if (t < 256) {
        if (p0 + t < total) {
          int gi = (int)(skey[p0 + t] & 1023u);
          int e = (b<<10) + gi;
          PC r = proj_cull(e, means, opac, scales, rots, vm, pm);
          recA[t] = make_float4(r.px, r.py, r.A, r.B);
          recB[t] = make_float4(r.C, r.op, __int_as_float(gi), 0.f);
        }
      } else {
        int ts = t - 256;
        if (p0 + ts < total) {
          int gi = (int)(skey[p0 + ts] & 1023u);
          int e = (b<<10) + gi;
          float col[3]; sh_color(e, sh, means, campos, col);
          colC[ts] = make_float4(col[0], col[1], col[2], 0.f);
        }
      }
      __syncthreads();

      for (int c0 = 0; c0 < lim; c0 += 32) {
        int cc = min(32, lim - c0);
        if (t < 256) {
          for (int i = 0; i < cc; ++i) {
            float4 qa = recA[c0+i], qb = recB[c0+i], qc = colC[c0+i];
            float dx = qa.x - fxp, dy = qa.y - fyp;
            float power = -0.5f*(qa.z*dx*dx + qb.x*dy*dy) - qa.w*dx*dy;
            float alpha = fminf(0.99f, qb.y * __expf(power));
            bool keep = (power <= 0.0f) && (alpha >= (1.0f/255.0f));
            float w_ = keep ? alpha * T : 0.0f;
            a0 += w_*qc.x; a1 += w_*qc.y; a2 += w_*qc.z;
            T -= w_;
            wmat[i][t] = w_;
          }
        }
        __syncthreads();
        if (t < 256) {
          int row = t >> 3, j = t & 7;
          if (row < cc) {
            float e0=0.f, e1=0.f, e2=0.f, ew=0.f;
            #pragma unroll 8
            for (int k = 0; k < 32; ++k) {
              int p = j + 8*k;
              float w_ = wmat[row][p];
              float4 tg = stgt[p];
              e0 += w_*tg.x; e1 += w_*tg.y; e2 += w_*tg.z; ew += w_;
            }
            #pragma unroll
            for (int o = 4; o; o >>= 1) {
              e0 += __shfl_down(e0, o, 8); e1 += __shfl_down(e1, o, 8);
              e2 += __shfl_down(e2, o, 8); ew += __shfl_down(ew, o, 8);
            }
            if (j == 0) {
              int idx = p0 + c0 + row;
              pgid[blk*PG + idx] = __float_as_int(recB[c0+row].z);
              pval[blk*PG + idx] = make_float4(e0, e1, e2, ew);
            }
          }
        }
        __syncthreads();
      }
    }

    if (t < 256) {
      out[((b*3+0)*HI + yi)*WI + xi] = a0 + T * bg[b*3+0];
      out[((b*3+1)*HI + yi)*WI + xi] = a1 + T * bg[b*3+1];
      out[((b*3+2)*HI + yi)*WI + xi] = a2 + T * bg[b*3+2];
      out[OFF_ALPHA + (b*HI + yi)*WI + xi] = 1.0f - T;
    }

    __syncthreads();
    if (t == 0) {
      __threadfence();
      atomicExch(&flags[blk], MAGIC_HI | (unsigned long long)total);
    }
    return;
  }

  // ==================== reducer block (512 thr) ====================
  const int r = blk - NTILES;              // 0..15
  const int batch = r >> 3, seg = r & 7;   // owns gaussians [seg*128, seg*128+128)

  if (t < 128) {
    int e_own = (batch<<10) + seg*128 + t;
    PC g = proj_cull(e_own, means, opac, scales, rots, vm, pm);
    out[OFF_RADII + e_own] = g.radii;
  }

  float* acc = &wmat[0][0];                // 128*4 = 512 floats
  acc[t] = 0.f;

  if (t < 64) {
    unsigned long long v;
    do { v = atomicAdd(&flags[batch*64 + t], 0ull);
         if ((v & MASK_HI) != MAGIC_HI) __builtin_amdgcn_s_sleep(1);
    } while ((v & MASK_HI) != MAGIC_HI);
    scnt[t] = (int)(v & 0xFFFFull);
  }
  __syncthreads();
  __threadfence();

  if (t == 0) {
    int s = 0;
    for (int i = 0; i < 64; ++i) { soff[i] = s; s += scnt[i]; }
    soff[64] = s;
  }
  __syncthreads();
  int E = soff[64];

  for (int idx = t; idx < E; idx += 512) {
    int lo = 0, hi = 63;
    while (lo < hi) { int mid = (lo+hi+1) >> 1; if (soff[mid] <= idx) lo = mid; else hi = mid-1; }
    int tb = batch*64 + lo;
    int j = idx - soff[lo];
    int gi = pgid[tb*PG + j];
    if ((gi >> 7) == seg) {
      float4 v = pval[tb*PG + j];
      int s = gi & 127;
      atomicAdd(&acc[s*4+0], v.x);
      atomicAdd(&acc[s*4+1], v.y);
      atomicAdd(&acc[s*4+2], v.z);
      atomicAdd(&acc[s*4+3], v.w);
    }
  }
  __syncthreads();

  if (t < 128) {
    int e_own = (batch<<10) + seg*128 + t;
    out[OFF_ESTC + e_own*3 + 0] = acc[t*4+0];
    out[OFF_ESTC + e_own*3 + 1] = acc[t*4+1];
    out[OFF_ESTC + e_own*3 + 2] = acc[t*4+2];
    out[OFF_ESTW + e_own]       = acc[t*4+3];
  }
}

extern "C" void kernel_launch(void* const* d_in, const int* in_sizes, int n_in,
                              void* d_out, int out_size, void* d_ws, size_t ws_size,
                              hipStream_t stream) {
  const float* means  = (const float*)d_in[0];
  const float* sh     = (const float*)d_in[1];
  const float* opac   = (const float*)d_in[2];
  const float* scales = (const float*)d_in[3];
  const float* rots   = (const float*)d_in[4];
  const float* target = (const float*)d_in[5];
  const float* bg     = (const float*)d_in[6];
  const float* vm     = (const float*)d_in[7];
  const float* pm     = (const float*)d_in[8];
  const float* campos = (const float*)d_in[9];
  float* out = (float*)d_out;

  float4* pval = (float4*)d_ws;                                        // 2 MB
  unsigned long long* flags = (unsigned long long*)(pval + NTILES*PG); // 1 KB
  int* pgid = (int*)(flags + NTILES);                                  // 512 KB

  fused_kernel<<<NTILES + NRED, 512, 0, stream>>>(
      means, sh, opac, scales, rots, vm, pm, campos, target, bg,
      pval, flags, pgid, out);
}

// Round 14
// 20.292 us; speedup vs baseline: 1.3728x; 1.0004x over previous
//
#include <hip/hip_runtime.h>
#include <math.h>

#define HI 128
#define WI 128
#define BB 2
#define PG 1024
#define NE (BB*PG)
#define NTILES 128          /* 2 batches x 64 tiles of 16x16 */
#define NRED 16             /* 2 batches x 8 segments of 128 gaussians */
#define MAGIC_HI 0xFEEDFACECAFE0000ULL
#define MASK_HI  0xFFFFFFFFFFFF0000ULL

#define OFF_ALPHA (BB*3*HI*WI)            /* 98304  */
#define OFF_ESTC  (OFF_ALPHA + BB*HI*WI)  /* 131072 */
#define OFF_ESTW  (OFF_ESTC + BB*PG*3)    /* 137216 */
#define OFF_RADII (OFF_ESTW + BB*PG)      /* 139264 */

struct PC {
  float px, py, ex, ey;
  float A, B, C, op;
  unsigned key;
  float radii;
};

__device__ __forceinline__ PC proj_cull(int e,
    const float* __restrict__ means, const float* __restrict__ opac,
    const float* __restrict__ scales, const float* __restrict__ rots,
    const float* __restrict__ vm, const float* __restrict__ pm)
{
  PC o;
  float mx = means[e*3+0], my = means[e*3+1], mz = means[e*3+2];

  float hom0 = pm[0]*mx + pm[1]*my + pm[2]*mz + pm[3];
  float hom1 = pm[4]*mx + pm[5]*my + pm[6]*mz + pm[7];
  float hom3 = pm[12]*mx + pm[13]*my + pm[14]*mz + pm[15];
  float p_w  = 1.0f / (hom3 + 1e-7f);
  float pp0 = hom0 * p_w, pp1 = hom1 * p_w;

  float pv0   = vm[0]*mx + vm[1]*my + vm[2]*mz  + vm[3];
  float pv1   = vm[4]*mx + vm[5]*my + vm[6]*mz  + vm[7];
  float depth = vm[8]*mx + vm[9]*my + vm[10]*mz + vm[11];

  float qr = rots[e*4+0], qx = rots[e*4+1], qy = rots[e*4+2], qz = rots[e*4+3];
  float qn = sqrtf(qr*qr + qx*qx + qy*qy + qz*qz);
  qr /= qn; qx /= qn; qy /= qn; qz /= qn;
  float R00 = 1.0f-2.0f*(qy*qy+qz*qz), R01 = 2.0f*(qx*qy-qr*qz), R02 = 2.0f*(qx*qz+qr*qy);
  float R10 = 2.0f*(qx*qy+qr*qz), R11 = 1.0f-2.0f*(qx*qx+qz*qz), R12 = 2.0f*(qy*qz-qr*qx);
  float R20 = 2.0f*(qx*qz-qr*qy), R21 = 2.0f*(qy*qz+qr*qx), R22 = 1.0f-2.0f*(qx*qx+qy*qy);

  float s0 = scales[e*3+0], s1 = scales[e*3+1], s2 = scales[e*3+2];
  float M00=R00*s0, M01=R01*s1, M02=R02*s2;
  float M10=R10*s0, M11=R11*s1, M12=R12*s2;
  float M20=R20*s0, M21=R21*s1, M22=R22*s2;
  float S00 = M00*M00+M01*M01+M02*M02;
  float S01 = M00*M10+M01*M11+M02*M12;
  float S02 = M00*M20+M01*M21+M02*M22;
  float S11 = M10*M10+M11*M11+M12*M12;
  float S12 = M10*M20+M11*M21+M12*M22;
  float S22 = M20*M20+M21*M21+M22*M22;

  const float fx = 128.0f, fyc = 128.0f;
  float tz = depth;
  float txc = fminf(fmaxf(pv0/tz, -0.65f), 0.65f) * tz;
  float tyc = fminf(fmaxf(pv1/tz, -0.65f), 0.65f) * tz;
  float J00 = fx/tz,  J02 = -fx*txc/(tz*tz);
  float J11 = fyc/tz, J12 = -fyc*tyc/(tz*tz);

  float T00 = J00*vm[0] + J02*vm[8];
  float T01 = J00*vm[1] + J02*vm[9];
  float T02 = J00*vm[2] + J02*vm[10];
  float T10 = J11*vm[4] + J12*vm[8];
  float T11 = J11*vm[5] + J12*vm[9];
  float T12 = J11*vm[6] + J12*vm[10];

  float TS00 = T00*S00 + T01*S01 + T02*S02;
  float TS01 = T00*S01 + T01*S11 + T02*S12;
  float TS02 = T00*S02 + T01*S12 + T02*S22;
  float TS10 = T10*S00 + T11*S01 + T12*S02;
  float TS11 = T10*S01 + T11*S11 + T12*S12;
  float TS12 = T10*S02 + T11*S12 + T12*S22;

  float c00 = TS00*T00 + TS01*T01 + TS02*T02 + 0.3f;
  float c01 = TS00*T10 + TS01*T11 + TS02*T12;
  float c11 = TS10*T10 + TS11*T11 + TS12*T12 + 0.3f;

  float det = c00*c11 - c01*c01;
  bool valid = (depth > 0.2f) && (det > 1e-12f);
  float inv_det = 1.0f / (det > 1e-12f ? det : 1.0f);
  o.A =  c11 * inv_det;
  o.B = -c01 * inv_det;
  o.C =  c00 * inv_det;
  float mid = 0.5f * (c00 + c11);
  float lam = mid + sqrtf(fmaxf(mid*mid - det, 0.1f));
  o.radii = valid ? ceilf(3.0f * sqrtf(lam)) : 0.0f;

  o.px = ((pp0 + 1.0f)*WI - 1.0f)*0.5f;
  o.py = ((pp1 + 1.0f)*HI - 1.0f)*0.5f;

  float opv = opac[e];
  o.op = opv;
  float tau = logf(255.0f * opv);
  bool rok = valid && (tau > 0.0f);
  o.ex = rok ? sqrtf(2.0f*tau*c00) + 0.02f : -1e9f;
  o.ey = rok ? sqrtf(2.0f*tau*c11) + 0.02f : -1e9f;

  unsigned u = __float_as_uint(depth);
  o.key = (u >> 31) ? ~u : (u | 0x80000000u);
  return o;
}

__device__ __forceinline__ void sh_color(int e,
    const float* __restrict__ sh, const float* __restrict__ means,
    const float* __restrict__ campos, float col[3])
{
  float mx = means[e*3+0], my = means[e*3+1], mz = means[e*3+2];
  float dxr = mx - campos[0], dyr = my - campos[1], dzr = mz - campos[2];
  float dn = sqrtf(dxr*dxr + dyr*dyr + dzr*dzr);
  float x = dxr/dn, y = dyr/dn, z = dzr/dn;
  float xx=x*x, yy=y*y, zz=z*z, xy=x*y, yz=y*z, xz=x*z;
  const float* S = sh + e*48;
  #pragma unroll
  for (int c = 0; c < 3; ++c) {
    float r = 0.28209479177387814f * S[0+c];
    r -= 0.4886025119029199f * y * S[3+c];
    r += 0.4886025119029199f * z * S[6+c];
    r -= 0.4886025119029199f * x * S[9+c];
    r += 1.0925484305920792f  * xy * S[12+c];
    r += -1.0925484305920792f * yz * S[15+c];
    r += 0.31539156525252005f * (2.0f*zz-xx-yy) * S[18+c];
    r += -1.0925484305920792f * xz * S[21+c];
    r += 0.5462742152960396f  * (xx-yy) * S[24+c];
    r += -0.5900435899266435f * y * (3.0f*xx-yy) * S[27+c];
    r += 2.890611442640554f   * xy * z * S[30+c];
    r += -0.4570457994644658f * y * (4.0f*zz-xx-yy) * S[33+c];
    r += 0.3731763325901154f  * z * (2.0f*zz-3.0f*xx-3.0f*yy) * S[36+c];
    r += -0.4570457994644658f * x * (4.0f*zz-xx-yy) * S[39+c];
    r += 1.445305721320277f   * z * (xx-yy) * S[42+c];
    r += -0.5900435899266435f * x * (xx-3.0f*yy) * S[45+c];
    col[c] = fmaxf(r + 0.5f, 0.0f);
  }
}

// in-register 64-element bitonic sort across one wave; dir=true ascending
__device__ __forceinline__ unsigned long long wave_sort64(
    unsigned long long v, int ln, bool asc)
{
  #pragma unroll
  for (int k = 2; k <= 64; k <<= 1) {
    bool dirAsc = (((ln & k) == 0)) == asc;
    #pragma unroll
    for (int j = k >> 1; j > 0; j >>= 1) {
      unsigned long long o = __shfl_xor(v, j, 64);
      bool takeMin = (((ln & j) == 0) == dirAsc);
      bool less = v < o;
      v = (takeMin == less) ? v : o;
    }
  }
  return v;
}

// in-register bitonic MERGE of a 64-length bitonic sequence, ascending
__device__ __forceinline__ unsigned long long wave_merge64(
    unsigned long long v, int ln)
{
  #pragma unroll
  for (int j = 32; j > 0; j >>= 1) {
    unsigned long long o = __shfl_xor(v, j, 64);
    bool takeMin = ((ln & j) == 0);
    bool less = v < o;
    v = (takeMin == less) ? v : o;
  }
  return v;
}

__global__ __launch_bounds__(512) void fused_kernel(
    const float* __restrict__ means, const float* __restrict__ sh,
    const float* __restrict__ opac, const float* __restrict__ scales,
    const float* __restrict__ rots, const float* __restrict__ vm,
    const float* __restrict__ pm, const float* __restrict__ campos,
    const float* __restrict__ target, const float* __restrict__ bg,
    float4* __restrict__ pval, unsigned long long* __restrict__ flags,
    int* __restrict__ pgid, float* __restrict__ out)
{
  const int t = threadIdx.x;
  const int wv = t >> 6, ln = t & 63;
  const int blk = blockIdx.x;

  __shared__ unsigned long long skey[PG];
  __shared__ float4 recA[256], recB[256], colC[256], stgt[256];
  __shared__ float  wmat[32][264];          /* tile: w matrix; reducer: acc */
  __shared__ int    scount;
  __shared__ int    scnt[64], soff[65];

  if (blk < NTILES) {
    // ==================== tile block (512 thr, 256 px) ====================
    const int b = blk >> 6, tile = blk & 63;
    const int tx0i = (tile & 7) * 16, ty0i = (tile >> 3) * 16;
    const int xi = tx0i + (t & 15), yi = ty0i + ((t >> 4) & 15);
    const float fxp = (float)xi, fyp = (float)yi;
    const float rx0 = (float)tx0i, ry0 = (float)ty0i;

    if (t == 0) scount = 0;
    if (t < 256) {
      stgt[t] = make_float4(target[((b*3+0)*HI + yi)*WI + xi],
                            target[((b*3+1)*HI + yi)*WI + xi],
                            target[((b*3+2)*HI + yi)*WI + xi], 1.0f);
    }
    __syncthreads();

    // scan: 2 gaussians per thread (1024 total)
    for (int k = 0; k < 2; ++k) {
      int ci = k*512 + t;
      PC r = proj_cull((b<<10)+ci, means, opac, scales, rots, vm, pm);
      bool ok = (r.px + r.ex >= rx0) && (r.px - r.ex <= rx0 + 15.0f)
             && (r.py + r.ey >= ry0) && (r.py - r.ey <= ry0 + 15.0f);
      if (ok) {
        int pos = atomicAdd(&scount, 1);
        skey[pos] = (((unsigned long long)r.key) << 10) | (unsigned)ci;
      }
    }
    __syncthreads();
    int total = scount;

    // ---- sort survivors by (depth,idx) ----
    if (total > 1) {
      if (total <= 64) {
        if (wv == 0) {
          unsigned long long v = (ln < total) ? skey[ln] : ~0ull;
          v = wave_sort64(v, ln, true);
          if (ln < total) skey[ln] = v;
        }
        __syncthreads();
      } else if (total <= 128) {
        // 2-barrier hybrid: wave0 asc[0,64), wave1 desc[64,128), exchange, merge
        if (wv < 2) {
          int idx = wv*64 + ln;
          unsigned long long v = (idx < total) ? skey[idx] : ~0ull;
          v = wave_sort64(v, ln, wv == 0);
          skey[idx] = v;
        }
        __syncthreads();
        if (wv < 2) {
          unsigned long long a = skey[ln], q = skey[64 + ln];
          unsigned long long mn = (a < q) ? a : q;
          unsigned long long mx = (a < q) ? q : a;
          unsigned long long v = (wv == 0) ? mn : mx;
          v = wave_merge64(v, ln);
          skey[wv*64 + ln] = v;
        }
        __syncthreads();
      } else {
        int M = 64; while (M < total) M <<= 1;
        for (int i = total + t; i < M; i += 512) skey[i] = ~0ull;
        __syncthreads();
        for (int k = 2; k <= M; k <<= 1)
          for (int j = k >> 1; j > 0; j >>= 1) {
            for (int base = t; base < M; base += 512) {
              int ixj = base ^ j;
              if (ixj > base) {
                unsigned long long a = skey[base], q = skey[ixj];
                bool up = ((base & k) == 0);
                if ((a > q) == up) { skey[base] = q; skey[ixj] = a; }
              }
            }
            __syncthreads();
          }
      }
    }

    float T = 1.0f, a0 = 0.f, a1 = 0.f, a2 = 0.f;

    for (int p0 = 0; p0 < total; p0 += 256) {
      int lim = min(256, total - p0);
      // split stage: lower half does conic record, upper half does SH color
      if (t < 256) {
        if (p0 + t < total) {
          int gi = (int)(skey[p0 + t] & 1023u);
          int e = (b<<10) + gi;
          PC r = proj_cull(e, means, opac, scales, rots, vm, pm);
          recA[t] = make_float4(r.px, r.py, r.A, r.B);
          recB[t] = make_float4(r.C, r.op, __int_as_float(gi), 0.f);
        }
      } else {
        int ts = t - 256;
        if (p0 + ts < total) {
          int gi = (int)(skey[p0 + ts] & 1023u);
          int e = (b<<10) + gi;
          float col[3]; sh_color(e, sh, means, campos, col);
          colC[ts] = make_float4(col[0], col[1], col[2], 0.f);
        }
      }
      __syncthreads();

      for (int c0 = 0; c0 < lim; c0 += 32) {
        int cc = min(32, lim - c0);
        if (t < 256) {
          for (int i = 0; i < cc; ++i) {
            float4 qa = recA[c0+i], qb = recB[c0+i], qc = colC[c0+i];
            float dx = qa.x - fxp, dy = qa.y - fyp;
            float power = -0.5f*(qa.z*dx*dx + qb.x*dy*dy) - qa.w*dx*dy;
            float alpha = fminf(0.99f, qb.y * __expf(power));
            bool keep = (power <= 0.0f) && (alpha >= (1.0f/255.0f));
            float w_ = keep ? alpha * T : 0.0f;
            a0 += w_*qc.x; a1 += w_*qc.y; a2 += w_*qc.z;
            T -= w_;
            wmat[i][t] = w_;
          }
        }
        __syncthreads();
        if (t < 256) {
          int row = t >> 3, j = t & 7;
          if (row < cc) {
            float e0=0.f, e1=0.f, e2=0.f, ew=0.f;
            #pragma unroll 8
            for (int k = 0; k < 32; ++k) {
              int p = j + 8*k;
              float w_ = wmat[row][p];
              float4 tg = stgt[p];
              e0 += w_*tg.x; e1 += w_*tg.y; e2 += w_*tg.z; ew += w_;
            }
            #pragma unroll
            for (int o = 4; o; o >>= 1) {
              e0 += __shfl_down(e0, o, 8); e1 += __shfl_down(e1, o, 8);
              e2 += __shfl_down(e2, o, 8); ew += __shfl_down(ew, o, 8);
            }
            if (j == 0) {
              int idx = p0 + c0 + row;
              pgid[blk*PG + idx] = __float_as_int(recB[c0+row].z);
              pval[blk*PG + idx] = make_float4(e0, e1, e2, ew);
            }
          }
        }
        __syncthreads();
      }
    }

    if (t < 256) {
      out[((b*3+0)*HI + yi)*WI + xi] = a0 + T * bg[b*3+0];
      out[((b*3+1)*HI + yi)*WI + xi] = a1 + T * bg[b*3+1];
      out[((b*3+2)*HI + yi)*WI + xi] = a2 + T * bg[b*3+2];
      out[OFF_ALPHA + (b*HI + yi)*WI + xi] = 1.0f - T;
    }

    __syncthreads();
    if (t == 0) {
      __threadfence();
      atomicExch(&flags[blk], MAGIC_HI | (unsigned long long)total);
    }
    return;
  }

  // ==================== reducer block (512 thr) ====================
  const int r = blk - NTILES;              // 0..15
  const int batch = r >> 3, seg = r & 7;   // owns gaussians [seg*128, seg*128+128)

  if (t < 128) {
    int e_own = (batch<<10) + seg*128 + t;
    PC g = proj_cull(e_own, means, opac, scales, rots, vm, pm);
    out[OFF_RADII + e_own] = g.radii;
  }

  float* acc = &wmat[0][0];                // 128*4 = 512 floats
  acc[t] = 0.f;

  if (t < 64) {
    unsigned long long v;
    do { v = atomicAdd(&flags[batch*64 + t], 0ull);
         if ((v & MASK_HI) != MAGIC_HI) __builtin_amdgcn_s_sleep(1);
    } while ((v & MASK_HI) != MAGIC_HI);
    scnt[t] = (int)(v & 0xFFFFull);
  }
  __syncthreads();
  __threadfence();

  if (t == 0) {
    int s = 0;
    for (int i = 0; i < 64; ++i) { soff[i] = s; s += scnt[i]; }
    soff[64] = s;
  }
  __syncthreads();
  int E = soff[64];

  for (int idx = t; idx < E; idx += 512) {
    int lo = 0, hi = 63;
    while (lo < hi) { int mid = (lo+hi+1) >> 1; if (soff[mid] <= idx) lo = mid; else hi = mid-1; }
    int tb = batch*64 + lo;
    int j = idx - soff[lo];
    int gi = pgid[tb*PG + j];
    if ((gi >> 7) == seg) {
      float4 v = pval[tb*PG + j];
      int s = gi & 127;
      atomicAdd(&acc[s*4+0], v.x);
      atomicAdd(&acc[s*4+1], v.y);
      atomicAdd(&acc[s*4+2], v.z);
      atomicAdd(&acc[s*4+3], v.w);
    }
  }
  __syncthreads();

  if (t < 128) {
    int e_own = (batch<<10) + seg*128 + t;
    out[OFF_ESTC + e_own*3 + 0] = acc[t*4+0];
    out[OFF_ESTC + e_own*3 + 1] = acc[t*4+1];
    out[OFF_ESTC + e_own*3 + 2] = acc[t*4+2];
    out[OFF_ESTW + e_own]       = acc[t*4+3];
  }
}

extern "C" void kernel_launch(void* const* d_in, const int* in_sizes, int n_in,
                              void* d_out, int out_size, void* d_ws, size_t ws_size,
                              hipStream_t stream) {
  const float* means  = (const float*)d_in[0];
  const float* sh     = (const float*)d_in[1];
  const float* opac   = (const float*)d_in[2];
  const float* scales = (const float*)d_in[3];
  const float* rots   = (const float*)d_in[4];
  const float* target = (const float*)d_in[5];
  const float* bg     = (const float*)d_in[6];
  const float* vm     = (const float*)d_in[7];
  const float* pm     = (const float*)d_in[8];
  const float* campos = (const float*)d_in[9];
  float* out = (float*)d_out;

  float4* pval = (float4*)d_ws;                                        // 2 MB
  unsigned long long* flags = (unsigned long long*)(pval + NTILES*PG); // 1 KB
  int* pgid = (int*)(flags + NTILES);                                  // 512 KB

  fused_kernel<<<NTILES + NRED, 512, 0, stream>>>(
      means, sh, opac, scales, rots, vm, pm, campos, target, bg,
      pval, flags, pgid, out);
}